// Round 7
// baseline (784.921 us; speedup 1.0000x reference)
//
#include <hip/hip_runtime.h>
#include <hip/hip_bf16.h>

#define H 128
#define NHEADS 2
#define DK 96
#define DV 96
#define DFF 2048
#define VOUT 10000
#define VOUT_PAD 10112        // 79 * 128, zero-padded rows in Wt
#define NB 256
#define TT 43
#define NT (NB * TT)          // 11008
#define MD (NHEADS * DV)      // 192
#define MDP 256               // multi padded cols (K for woln1 GEMM)
#define QKVC 640              // packed qkv cols: 576 used + 64 pad

typedef short short8v __attribute__((ext_vector_type(8)));
typedef unsigned short ushort8v __attribute__((ext_vector_type(8)));
typedef float f32x4 __attribute__((ext_vector_type(4)));

__device__ __forceinline__ unsigned short f2bf(float f) {
    unsigned b = __float_as_uint(f);
    unsigned r = b + 0x7FFFu + ((b >> 16) & 1u);   // RTNE
    return (unsigned short)(r >> 16);
}
__device__ __forceinline__ float bf2f(unsigned short u) {
    return __uint_as_float((unsigned)u << 16);
}

// ---------------------------------------------------------------- embed
__global__ __launch_bounds__(256) void embed_kernel(
    const int* __restrict__ inputs, const float* __restrict__ emb,
    const float* __restrict__ pos, float* __restrict__ x) {
    int i = blockIdx.x * 256 + threadIdx.x;   // grid sized exactly NT*H/256
    int h = i & (H - 1);
    int nt = i >> 7;
    int t = nt % TT;
    x[i] = emb[inputs[nt] * H + h] + pos[t * H + h];
}

// ---------------------------------------------------------------- pack Wq/Wk/Wv -> Wqkv_t[640][128] bf16 + bias[640]
// row r: seg=r/96 (q0,q1,k0,k1,v0,v1), d=r%96; rows 576+ zero
__global__ __launch_bounds__(256) void wqkv_pack_kernel(
    const float* __restrict__ Wq, const float* __restrict__ bq,
    const float* __restrict__ Wk, const float* __restrict__ bk,
    const float* __restrict__ Wv, const float* __restrict__ bv,
    unsigned short* __restrict__ Wt, float* __restrict__ bias) {
    int row = blockIdx.x * 256 + threadIdx.x;   // grid = 3 blocks
    if (row >= QKVC) return;
    unsigned short* dst = Wt + (size_t)row * H;
    if (row < 576) {
        int seg = row / 96;
        int d = row - seg * 96;
        int which = seg >> 1;                    // 0=q 1=k 2=v
        int head = seg & 1;
        const float* W  = (which == 0) ? Wq : (which == 1) ? Wk : Wv;
        const float* bi = (which == 0) ? bq : (which == 1) ? bk : bv;
        for (int h = 0; h < H; ++h) dst[h] = f2bf(W[((size_t)head * H + h) * DK + d]);
        bias[row] = bi[head * DK + d];
    } else {
        for (int h = 0; h < H; ++h) dst[h] = 0;
        bias[row] = 0.f;
    }
}

// ---------------------------------------------------------------- QKV GEMM (MFMA): qkvb = x @ Wqkv + bias, bf16 out
// A = x fp32 [NT][128] (bf16 in staging); B = Wqkv_t[640][128] bf16 row-copy.
__global__ __launch_bounds__(256) void qkv_mfma_kernel(
    const float* __restrict__ x, const unsigned short* __restrict__ Wt,
    const float* __restrict__ bias, unsigned short* __restrict__ qkvb) {
    __shared__ __align__(16) unsigned short As[128][128];  // 32 KB
    __shared__ __align__(16) unsigned short Bt[128][128];  // 32 KB
    int tid = threadIdx.x;
    int n0 = blockIdx.x * 128;                 // qkv-col tile (0..4)
    int m0 = blockIdx.y * 128;                 // token tile
    // stage A: fp32 -> bf16, swizzled octets
    for (int qc = tid; qc < 2048; qc += 256) {
        int row = qc >> 4, o = qc & 15;
        const float4* src = (const float4*)(x + (size_t)(m0 + row) * H + o * 8);
        float4 f0 = src[0], f1 = src[1];
        ushort8v v;
        v[0] = f2bf(f0.x); v[1] = f2bf(f0.y); v[2] = f2bf(f0.z); v[3] = f2bf(f0.w);
        v[4] = f2bf(f1.x); v[5] = f2bf(f1.y); v[6] = f2bf(f1.z); v[7] = f2bf(f1.w);
        int po = (o & 8) | ((o ^ row) & 7);
        *(ushort8v*)&As[row][po * 8] = v;
    }
    // stage B: row copy (transposed weights)
    {
        const ushort8v* B8 = (const ushort8v*)(Wt + (size_t)n0 * H);
        for (int qc = tid; qc < 2048; qc += 256) {
            int row = qc >> 4, o = qc & 15;
            int po = (o & 8) | ((o ^ row) & 7);
            *(ushort8v*)&Bt[row][po * 8] = B8[qc];
        }
    }
    __syncthreads();
    int lane = tid & 63;
    int w = tid >> 6;
    int wr = w >> 1, wc = w & 1;
    int rl = lane & 15, quad = lane >> 4;
    f32x4 acc[4][4];
    #pragma unroll
    for (int i = 0; i < 4; ++i)
        #pragma unroll
        for (int j = 0; j < 4; ++j) acc[i][j] = (f32x4){0.f, 0.f, 0.f, 0.f};
    #pragma unroll
    for (int kk = 0; kk < 4; ++kk) {
        int o = kk * 4 + quad;
        short8v a[4], b[4];
        #pragma unroll
        for (int mi = 0; mi < 4; ++mi) {
            int row = wr * 64 + mi * 16 + rl;
            int po = (o & 8) | ((o ^ row) & 7);
            a[mi] = *(const short8v*)&As[row][po * 8];
        }
        #pragma unroll
        for (int ni = 0; ni < 4; ++ni) {
            int cc = wc * 64 + ni * 16 + rl;
            int po = (o & 8) | ((o ^ cc) & 7);
            b[ni] = *(const short8v*)&Bt[cc][po * 8];
        }
        #pragma unroll
        for (int mi = 0; mi < 4; ++mi)
            #pragma unroll
            for (int ni = 0; ni < 4; ++ni)
                acc[mi][ni] = __builtin_amdgcn_mfma_f32_16x16x32_bf16(
                    a[mi], b[ni], acc[mi][ni], 0, 0, 0);
    }
    #pragma unroll
    for (int ni = 0; ni < 4; ++ni) {
        int col = n0 + wc * 64 + ni * 16 + rl;
        float bv = bias[col];
        #pragma unroll
        for (int mi = 0; mi < 4; ++mi) {
            int rbase = m0 + wr * 64 + mi * 16 + quad * 4;
            #pragma unroll
            for (int r = 0; r < 4; ++r)
                qkvb[(size_t)(rbase + r) * QKVC + col] = f2bf(acc[mi][ni][r] + bv);
        }
    }
}

// ---------------------------------------------------------------- attention core (reads packed bf16 qkv; multi -> bf16 [NT][256])
__global__ __launch_bounds__(256) void attn_core_kernel(
    const unsigned short* __restrict__ qkvb, unsigned short* __restrict__ multi_b) {
    int blk = blockIdx.x;
    int n = blk / NHEADS, a = blk % NHEADS;
    int tid = threadIdx.x;
    __shared__ float qs[TT][DK];
    __shared__ float ks2[TT][DK];
    __shared__ float vs[TT][DV];
    __shared__ float ss[TT][TT + 1];
    for (int i = tid; i < TT * DK; i += 256) {
        int t = i / DK, d = i - t * DK;
        size_t base = (size_t)(n * TT + t) * QKVC + a * DK;
        qs[t][d]  = bf2f(qkvb[base + d]);
        ks2[t][d] = bf2f(qkvb[base + 192 + d]);
        vs[t][d]  = bf2f(qkvb[base + 384 + d]);
    }
    __syncthreads();
    const float scale = rsqrtf((float)DK);
    for (int o = tid; o < TT * TT; o += 256) {
        int t = o / TT, s = o - t * TT;
        float acc = 0.f;
        #pragma unroll 8
        for (int d = 0; d < DK; ++d) acc += qs[t][d] * ks2[s][d];
        ss[t][s] = acc * scale;
    }
    __syncthreads();
    if (tid < TT) {
        float m = -1e30f;
        for (int s = 0; s < TT; ++s) m = fmaxf(m, ss[tid][s]);
        float sum = 0.f;
        for (int s = 0; s < TT; ++s) { float e = __expf(ss[tid][s] - m); ss[tid][s] = e; sum += e; }
        float inv = 1.0f / sum;
        for (int s = 0; s < TT; ++s) ss[tid][s] *= inv;
    }
    __syncthreads();
    for (int o = tid; o < TT * DV; o += 256) {
        int t = o / DV, d = o - t * DV;
        float acc = 0.f;
        #pragma unroll 8
        for (int s = 0; s < TT; ++s) acc += ss[t][s] * vs[s][d];
        multi_b[(size_t)(n * TT + t) * MDP + a * DV + d] = f2bf(acc);
    }
    // pad cols [MD,MDP) stay 0xAA poison: finite bf16, multiplied by zeroed Wo_pad rows
}

// ---------------------------------------------------------------- Wo [192][128] -> Wo_pad [256][128] f32 (zero pad rows)
__global__ __launch_bounds__(256) void wopad_kernel(
    const float* __restrict__ Wo, float* __restrict__ Wop) {
    int i = blockIdx.x * 256 + threadIdx.x;   // grid = 256*128/256 = 128
    int row = i >> 7, col = i & 127;
    Wop[i] = (row < MD) ? Wo[row * H + col] : 0.f;
}

// ---------------------------------------------------------------- Wo-GEMM + residual + LN1 (fused, MFMA)
// x1 = LN(x + multi_b @ Wo_pad + bo); K=256 in 2 chunks of 128.
__global__ __launch_bounds__(256) void woln1_mfma_kernel(
    const unsigned short* __restrict__ mb, const float* __restrict__ Wop,
    const float* __restrict__ bo, const float* __restrict__ x,
    const float* __restrict__ g, const float* __restrict__ bln,
    float* __restrict__ x1) {
    __shared__ __align__(16) unsigned short As[128][128];  // 32 KB
    __shared__ __align__(16) unsigned short Bt[128][128];  // 32 KB
    int tid = threadIdx.x;
    int m0 = blockIdx.x * 128;
    int lane = tid & 63;
    int w = tid >> 6;
    int wr = w >> 1, wc = w & 1;
    int rl = lane & 15, quad = lane >> 4;
    f32x4 acc[4][4];
    #pragma unroll
    for (int i = 0; i < 4; ++i)
        #pragma unroll
        for (int j = 0; j < 4; ++j) acc[i][j] = (f32x4){0.f, 0.f, 0.f, 0.f};
    for (int kc = 0; kc < 2; ++kc) {
        for (int qc = tid; qc < 2048; qc += 256) {
            int row = qc >> 4, o = qc & 15;
            ushort8v v = *(const ushort8v*)(mb + (size_t)(m0 + row) * MDP + kc * 128 + o * 8);
            int po = (o & 8) | ((o ^ row) & 7);
            *(ushort8v*)&As[row][po * 8] = v;
        }
        {
            int c = tid & 127;
            int kb = tid >> 7;
            #pragma unroll
            for (int p = 0; p < 8; ++p) {
                int o = kb + 2 * p;
                ushort8v v;
                #pragma unroll
                for (int j = 0; j < 8; ++j)
                    v[j] = f2bf(Wop[(size_t)(kc * 128 + o * 8 + j) * H + c]);
                int po = (o & 8) | ((o ^ c) & 7);
                *(ushort8v*)&Bt[c][po * 8] = v;
            }
        }
        __syncthreads();
        #pragma unroll
        for (int kk = 0; kk < 4; ++kk) {
            int o = kk * 4 + quad;
            short8v a[4], b[4];
            #pragma unroll
            for (int mi = 0; mi < 4; ++mi) {
                int row = wr * 64 + mi * 16 + rl;
                int po = (o & 8) | ((o ^ row) & 7);
                a[mi] = *(const short8v*)&As[row][po * 8];
            }
            #pragma unroll
            for (int ni = 0; ni < 4; ++ni) {
                int cc = wc * 64 + ni * 16 + rl;
                int po = (o & 8) | ((o ^ cc) & 7);
                b[ni] = *(const short8v*)&Bt[cc][po * 8];
            }
            #pragma unroll
            for (int mi = 0; mi < 4; ++mi)
                #pragma unroll
                for (int ni = 0; ni < 4; ++ni)
                    acc[mi][ni] = __builtin_amdgcn_mfma_f32_16x16x32_bf16(
                        a[mi], b[ni], acc[mi][ni], 0, 0, 0);
        }
        __syncthreads();   // also protects As before scratch reuse below
    }
    // ---- fused epilogue: y = acc + bo + x ; LN over H=128 per row
    float gg[4], bb[4], bov[4];
    #pragma unroll
    for (int ni = 0; ni < 4; ++ni) {
        int col = wc * 64 + ni * 16 + rl;
        gg[ni] = g[col]; bb[ni] = bln[col]; bov[ni] = bo[col];
    }
    float sy[4][4], sy2[4][4];
    #pragma unroll
    for (int mi = 0; mi < 4; ++mi)
        #pragma unroll
        for (int r = 0; r < 4; ++r) { sy[mi][r] = 0.f; sy2[mi][r] = 0.f; }
    #pragma unroll
    for (int mi = 0; mi < 4; ++mi) {
        #pragma unroll
        for (int r = 0; r < 4; ++r) {
            int row = wr * 64 + mi * 16 + quad * 4 + r;
            #pragma unroll
            for (int ni = 0; ni < 4; ++ni) {
                int col = wc * 64 + ni * 16 + rl;
                float y = acc[mi][ni][r] + bov[ni] + x[(size_t)(m0 + row) * H + col];
                acc[mi][ni][r] = y;
                sy[mi][r] += y;
                sy2[mi][r] += y * y;
            }
        }
    }
    #pragma unroll
    for (int mi = 0; mi < 4; ++mi)
        #pragma unroll
        for (int r = 0; r < 4; ++r) {
            #pragma unroll
            for (int m = 1; m < 16; m <<= 1) {
                sy[mi][r]  += __shfl_xor(sy[mi][r],  m);
                sy2[mi][r] += __shfl_xor(sy2[mi][r], m);
            }
        }
    float* scr = (float*)&As[0][0];
    if (rl == 0) {
        #pragma unroll
        for (int mi = 0; mi < 4; ++mi)
            #pragma unroll
            for (int r = 0; r < 4; ++r) {
                int row = wr * 64 + mi * 16 + quad * 4 + r;
                scr[wc * 128 + row]       = sy[mi][r];
                scr[256 + wc * 128 + row] = sy2[mi][r];
            }
    }
    __syncthreads();
    #pragma unroll
    for (int mi = 0; mi < 4; ++mi) {
        #pragma unroll
        for (int r = 0; r < 4; ++r) {
            int row = wr * 64 + mi * 16 + quad * 4 + r;
            float tsy  = scr[row] + scr[128 + row];
            float tsy2 = scr[256 + row] + scr[384 + row];
            float mean = tsy * (1.0f / H);
            float var  = tsy2 * (1.0f / H) - mean * mean;
            float rstd = rsqrtf(var + 1e-5f);
            #pragma unroll
            for (int ni = 0; ni < 4; ++ni) {
                int col = wc * 64 + ni * 16 + rl;
                x1[(size_t)(m0 + row) * H + col] =
                    (acc[mi][ni][r] - mean) * rstd * gg[ni] + bb[ni];
            }
        }
    }
}

// ---------------------------------------------------------------- FF GEMM1: h = relu(x1 @ W1 + b1), bf16 out
__global__ __launch_bounds__(256) void ffh_kernel(
    const float* __restrict__ x1, const float* __restrict__ W1,
    const float* __restrict__ b1, unsigned short* __restrict__ hb) {
    __shared__ __align__(16) unsigned short As[128][128];  // 32 KB
    __shared__ __align__(16) unsigned short Bt[128][128];  // 32 KB
    int tid = threadIdx.x;
    int n0 = blockIdx.x * 128;                 // ff-dim tile
    int m0 = blockIdx.y * 128;                 // token tile
    for (int qc = tid; qc < 2048; qc += 256) {
        int row = qc >> 4, o = qc & 15;
        const float4* src = (const float4*)(x1 + (size_t)(m0 + row) * H + o * 8);
        float4 f0 = src[0], f1 = src[1];
        ushort8v v;
        v[0] = f2bf(f0.x); v[1] = f2bf(f0.y); v[2] = f2bf(f0.z); v[3] = f2bf(f0.w);
        v[4] = f2bf(f1.x); v[5] = f2bf(f1.y); v[6] = f2bf(f1.z); v[7] = f2bf(f1.w);
        int po = (o & 8) | ((o ^ row) & 7);
        *(ushort8v*)&As[row][po * 8] = v;
    }
    {
        int c = tid & 127;
        int kb = tid >> 7;
        #pragma unroll
        for (int p = 0; p < 8; ++p) {
            int o = kb + 2 * p;
            ushort8v v;
            #pragma unroll
            for (int j = 0; j < 8; ++j)
                v[j] = f2bf(W1[(size_t)(o * 8 + j) * DFF + n0 + c]);
            int po = (o & 8) | ((o ^ c) & 7);
            *(ushort8v*)&Bt[c][po * 8] = v;
        }
    }
    __syncthreads();
    int lane = tid & 63;
    int w = tid >> 6;
    int wr = w >> 1, wc = w & 1;
    int rl = lane & 15, quad = lane >> 4;
    f32x4 acc[4][4];
    #pragma unroll
    for (int i = 0; i < 4; ++i)
        #pragma unroll
        for (int j = 0; j < 4; ++j) acc[i][j] = (f32x4){0.f, 0.f, 0.f, 0.f};
    #pragma unroll
    for (int kk = 0; kk < 4; ++kk) {
        int o = kk * 4 + quad;
        short8v a[4], b[4];
        #pragma unroll
        for (int mi = 0; mi < 4; ++mi) {
            int row = wr * 64 + mi * 16 + rl;
            int po = (o & 8) | ((o ^ row) & 7);
            a[mi] = *(const short8v*)&As[row][po * 8];
        }
        #pragma unroll
        for (int ni = 0; ni < 4; ++ni) {
            int cc = wc * 64 + ni * 16 + rl;
            int po = (o & 8) | ((o ^ cc) & 7);
            b[ni] = *(const short8v*)&Bt[cc][po * 8];
        }
        #pragma unroll
        for (int mi = 0; mi < 4; ++mi)
            #pragma unroll
            for (int ni = 0; ni < 4; ++ni)
                acc[mi][ni] = __builtin_amdgcn_mfma_f32_16x16x32_bf16(
                    a[mi], b[ni], acc[mi][ni], 0, 0, 0);
    }
    #pragma unroll
    for (int ni = 0; ni < 4; ++ni) {
        int col = n0 + wc * 64 + ni * 16 + rl;
        float bv = b1[col];
        #pragma unroll
        for (int mi = 0; mi < 4; ++mi) {
            int rbase = m0 + wr * 64 + mi * 16 + quad * 4;
            #pragma unroll
            for (int r = 0; r < 4; ++r)
                hb[(size_t)(rbase + r) * DFF + col] =
                    f2bf(fmaxf(acc[mi][ni][r] + bv, 0.f));
        }
    }
}

// ---------------------------------------------------------------- FF GEMM2 + residual + LN2 (fused): x2b = LN(h@W2 + b2 + x1)
__global__ __launch_bounds__(256) void ff2_ln2_kernel(
    const unsigned short* __restrict__ hb, const float* __restrict__ W2,
    const float* __restrict__ b2, const float* __restrict__ x1,
    const float* __restrict__ g, const float* __restrict__ bln,
    unsigned short* __restrict__ x2b) {
    __shared__ __align__(16) unsigned short As[128][128];  // 32 KB
    __shared__ __align__(16) unsigned short Bt[128][128];  // 32 KB
    int tid = threadIdx.x;
    int m0 = blockIdx.x * 128;
    int lane = tid & 63;
    int w = tid >> 6;
    int wr = w >> 1, wc = w & 1;
    int rl = lane & 15, quad = lane >> 4;
    f32x4 acc[4][4];
    #pragma unroll
    for (int i = 0; i < 4; ++i)
        #pragma unroll
        for (int j = 0; j < 4; ++j) acc[i][j] = (f32x4){0.f, 0.f, 0.f, 0.f};
    for (int kc = 0; kc < 16; ++kc) {
        for (int qc = tid; qc < 2048; qc += 256) {
            int row = qc >> 4, o = qc & 15;
            ushort8v v = *(const ushort8v*)(hb + (size_t)(m0 + row) * DFF + kc * 128 + o * 8);
            int po = (o & 8) | ((o ^ row) & 7);
            *(ushort8v*)&As[row][po * 8] = v;
        }
        {
            int c = tid & 127;
            int kb = tid >> 7;
            #pragma unroll
            for (int p = 0; p < 8; ++p) {
                int o = kb + 2 * p;
                ushort8v v;
                #pragma unroll
                for (int j = 0; j < 8; ++j)
                    v[j] = f2bf(W2[(size_t)(kc * 128 + o * 8 + j) * H + c]);
                int po = (o & 8) | ((o ^ c) & 7);
                *(ushort8v*)&Bt[c][po * 8] = v;
            }
        }
        __syncthreads();
        #pragma unroll
        for (int kk = 0; kk < 4; ++kk) {
            int o = kk * 4 + quad;
            short8v a[4], b[4];
            #pragma unroll
            for (int mi = 0; mi < 4; ++mi) {
                int row = wr * 64 + mi * 16 + rl;
                int po = (o & 8) | ((o ^ row) & 7);
                a[mi] = *(const short8v*)&As[row][po * 8];
            }
            #pragma unroll
            for (int ni = 0; ni < 4; ++ni) {
                int cc = wc * 64 + ni * 16 + rl;
                int po = (o & 8) | ((o ^ cc) & 7);
                b[ni] = *(const short8v*)&Bt[cc][po * 8];
            }
            #pragma unroll
            for (int mi = 0; mi < 4; ++mi)
                #pragma unroll
                for (int ni = 0; ni < 4; ++ni)
                    acc[mi][ni] = __builtin_amdgcn_mfma_f32_16x16x32_bf16(
                        a[mi], b[ni], acc[mi][ni], 0, 0, 0);
        }
        __syncthreads();   // after last iter, As is free for scratch reuse
    }
    // ---- fused epilogue: y = acc + b2 + x1 ; LN over H=128 per row; bf16 store
    float gg[4], bb[4], bov[4];
    #pragma unroll
    for (int ni = 0; ni < 4; ++ni) {
        int col = wc * 64 + ni * 16 + rl;
        gg[ni] = g[col]; bb[ni] = bln[col]; bov[ni] = b2[col];
    }
    float sy[4][4], sy2[4][4];
    #pragma unroll
    for (int mi = 0; mi < 4; ++mi)
        #pragma unroll
        for (int r = 0; r < 4; ++r) { sy[mi][r] = 0.f; sy2[mi][r] = 0.f; }
    #pragma unroll
    for (int mi = 0; mi < 4; ++mi) {
        #pragma unroll
        for (int r = 0; r < 4; ++r) {
            int row = wr * 64 + mi * 16 + quad * 4 + r;
            #pragma unroll
            for (int ni = 0; ni < 4; ++ni) {
                int col = wc * 64 + ni * 16 + rl;
                float y = acc[mi][ni][r] + bov[ni] + x1[(size_t)(m0 + row) * H + col];
                acc[mi][ni][r] = y;
                sy[mi][r] += y;
                sy2[mi][r] += y * y;
            }
        }
    }
    #pragma unroll
    for (int mi = 0; mi < 4; ++mi)
        #pragma unroll
        for (int r = 0; r < 4; ++r) {
            #pragma unroll
            for (int m = 1; m < 16; m <<= 1) {
                sy[mi][r]  += __shfl_xor(sy[mi][r],  m);
                sy2[mi][r] += __shfl_xor(sy2[mi][r], m);
            }
        }
    float* scr = (float*)&As[0][0];
    if (rl == 0) {
        #pragma unroll
        for (int mi = 0; mi < 4; ++mi)
            #pragma unroll
            for (int r = 0; r < 4; ++r) {
                int row = wr * 64 + mi * 16 + quad * 4 + r;
                scr[wc * 128 + row]       = sy[mi][r];
                scr[256 + wc * 128 + row] = sy2[mi][r];
            }
    }
    __syncthreads();
    #pragma unroll
    for (int mi = 0; mi < 4; ++mi) {
        #pragma unroll
        for (int r = 0; r < 4; ++r) {
            int row = wr * 64 + mi * 16 + quad * 4 + r;
            float tsy  = scr[row] + scr[128 + row];
            float tsy2 = scr[256 + row] + scr[384 + row];
            float mean = tsy * (1.0f / H);
            float var  = tsy2 * (1.0f / H) - mean * mean;
            float rstd = rsqrtf(var + 1e-5f);
            #pragma unroll
            for (int ni = 0; ni < 4; ++ni) {
                int col = wc * 64 + ni * 16 + rl;
                x2b[(size_t)(m0 + row) * H + col] =
                    f2bf((acc[mi][ni][r] - mean) * rstd * gg[ni] + bb[ni]);
            }
        }
    }
}

// ---------------------------------------------------------------- Wout fp32 [H][VOUT] -> bf16 transposed Wt[VOUT_PAD][H]
__global__ __launch_bounds__(256) void wtr_kernel(
    const float* __restrict__ W, unsigned short* __restrict__ Wt) {
    int n = blockIdx.x * 256 + threadIdx.x;   // grid = ceil(VOUT_PAD/256) = 40
    if (n >= VOUT_PAD) return;
    ushort8v* dst = (ushort8v*)(Wt + (size_t)n * H);
    if (n < VOUT) {
        #pragma unroll
        for (int k16 = 0; k16 < 16; ++k16) {
            ushort8v v;
            #pragma unroll
            for (int j = 0; j < 8; ++j)
                v[j] = f2bf(W[(size_t)(k16 * 8 + j) * VOUT + n]);
            dst[k16] = v;
        }
    } else {
        ushort8v z = {};
        #pragma unroll
        for (int k16 = 0; k16 < 16; ++k16) dst[k16] = z;
    }
}

// ---------------------------------------------------------------- vocab GEMM (bf16 MFMA)
__global__ __launch_bounds__(256) void out_gemm_mfma_kernel(
    const unsigned short* __restrict__ A, const unsigned short* __restrict__ Wt,
    const float* __restrict__ bias, float* __restrict__ C) {
    __shared__ __align__(16) unsigned short As[128][128];  // 32 KB
    __shared__ __align__(16) unsigned short Bt[128][128];  // 32 KB
    int tid = threadIdx.x;
    int n0 = blockIdx.x * 128;
    int m0 = blockIdx.y * 128;
    {
        const ushort8v* A8 = (const ushort8v*)(A + (size_t)m0 * H);
        for (int qc = tid; qc < 2048; qc += 256) {
            int row = qc >> 4, o = qc & 15;
            int po = (o & 8) | ((o ^ row) & 7);
            *(ushort8v*)&As[row][po * 8] = A8[qc];
        }
    }
    {
        const ushort8v* B8 = (const ushort8v*)(Wt + (size_t)n0 * H);
        for (int qc = tid; qc < 2048; qc += 256) {
            int row = qc >> 4, o = qc & 15;
            int po = (o & 8) | ((o ^ row) & 7);
            *(ushort8v*)&Bt[row][po * 8] = B8[qc];
        }
    }
    __syncthreads();
    int lane = tid & 63;
    int w = tid >> 6;
    int wr = w >> 1, wc = w & 1;
    int rl = lane & 15, quad = lane >> 4;
    f32x4 acc[4][4];
    #pragma unroll
    for (int i = 0; i < 4; ++i)
        #pragma unroll
        for (int j = 0; j < 4; ++j) acc[i][j] = (f32x4){0.f, 0.f, 0.f, 0.f};
    #pragma unroll
    for (int kk = 0; kk < 4; ++kk) {
        int o = kk * 4 + quad;
        short8v a[4], b[4];
        #pragma unroll
        for (int mi = 0; mi < 4; ++mi) {
            int row = wr * 64 + mi * 16 + rl;
            int po = (o & 8) | ((o ^ row) & 7);
            a[mi] = *(const short8v*)&As[row][po * 8];
        }
        #pragma unroll
        for (int ni = 0; ni < 4; ++ni) {
            int cc = wc * 64 + ni * 16 + rl;
            int po = (o & 8) | ((o ^ cc) & 7);
            b[ni] = *(const short8v*)&Bt[cc][po * 8];
        }
        #pragma unroll
        for (int mi = 0; mi < 4; ++mi)
            #pragma unroll
            for (int ni = 0; ni < 4; ++ni)
                acc[mi][ni] = __builtin_amdgcn_mfma_f32_16x16x32_bf16(
                    a[mi], b[ni], acc[mi][ni], 0, 0, 0);
    }
    #pragma unroll
    for (int ni = 0; ni < 4; ++ni) {
        int col = n0 + wc * 64 + ni * 16 + rl;
        if (col >= VOUT) continue;
        float bv = bias[col];
        #pragma unroll
        for (int mi = 0; mi < 4; ++mi) {
            int rbase = m0 + wr * 64 + mi * 16 + quad * 4;
            #pragma unroll
            for (int r = 0; r < 4; ++r)
                C[(size_t)(rbase + r) * VOUT + col] = acc[mi][ni][r] + bv;
        }
    }
}

// ---------------------------------------------------------------- launch
extern "C" void kernel_launch(void* const* d_in, const int* in_sizes, int n_in,
                              void* d_out, int out_size, void* d_ws, size_t ws_size,
                              hipStream_t stream) {
    const int*   inputs = (const int*)  d_in[0];
    const float* emb    = (const float*)d_in[1];
    const float* pos    = (const float*)d_in[2];
    const float* Wq     = (const float*)d_in[3];
    const float* bq     = (const float*)d_in[4];
    const float* Wk     = (const float*)d_in[5];
    const float* bk     = (const float*)d_in[6];
    const float* Wv     = (const float*)d_in[7];
    const float* bv     = (const float*)d_in[8];
    const float* Wo     = (const float*)d_in[9];
    const float* bo     = (const float*)d_in[10];
    const float* ln1g   = (const float*)d_in[11];
    const float* ln1b   = (const float*)d_in[12];
    const float* W1     = (const float*)d_in[13];
    const float* b1     = (const float*)d_in[14];
    const float* W2     = (const float*)d_in[15];
    const float* b2     = (const float*)d_in[16];
    const float* ln2g   = (const float*)d_in[17];
    const float* ln2b   = (const float*)d_in[18];
    const float* Wout   = (const float*)d_in[19];
    const float* bout   = (const float*)d_in[20];
    float* out = (float*)d_out;

    float* ws = (float*)d_ws;
    float* x      = ws;                                  // NT*H f32
    float* x1     = x + (size_t)NT * H;                  // NT*H f32
    float* Wo_pad = x1 + (size_t)NT * H;                 // MDP*H f32
    float* bqkv   = Wo_pad + (size_t)MDP * H;            // QKVC f32
    unsigned short* multi_b = (unsigned short*)(bqkv + QKVC);            // NT*MDP bf16
    unsigned short* x2b     = multi_b + (size_t)NT * MDP;                // NT*H bf16
    unsigned short* Woutb   = x2b + (size_t)NT * H;                      // VOUT_PAD*H bf16
    unsigned short* Wqkvb   = Woutb + (size_t)VOUT_PAD * H;              // QKVC*H bf16
    unsigned short* qkvb    = Wqkvb + (size_t)QKVC * H;                  // NT*QKVC bf16
    unsigned short* hb      = qkvb + (size_t)NT * QKVC;                  // NT*DFF bf16

    wqkv_pack_kernel<<<(QKVC + 255) / 256, 256, 0, stream>>>(
        Wq, bq, Wk, bk, Wv, bv, Wqkvb, bqkv);
    wopad_kernel<<<MDP * H / 256, 256, 0, stream>>>(Wo, Wo_pad);
    wtr_kernel<<<(VOUT_PAD + 255) / 256, 256, 0, stream>>>(Wout, Woutb);
    embed_kernel<<<NT * H / 256, 256, 0, stream>>>(inputs, emb, pos, x);
    dim3 gqkv(QKVC / 128, NT / 128);
    qkv_mfma_kernel<<<gqkv, 256, 0, stream>>>(x, Wqkvb, bqkv, qkvb);
    attn_core_kernel<<<NB * NHEADS, 256, 0, stream>>>(qkvb, multi_b);
    woln1_mfma_kernel<<<NT / 128, 256, 0, stream>>>(multi_b, Wo_pad, bo, x, ln1g, ln1b, x1);
    dim3 gff(DFF / 128, NT / 128);
    ffh_kernel<<<gff, 256, 0, stream>>>(x1, W1, b1, hb);
    ff2_ln2_kernel<<<NT / 128, 256, 0, stream>>>(hb, W2, b2, x1, ln2g, ln2b, x2b);
    dim3 g5((VOUT + 127) / 128, NT / 128);
    out_gemm_mfma_kernel<<<g5, 256, 0, stream>>>(x2b, Woutb, bout, out);
}

// Round 9
// 724.633 us; speedup vs baseline: 1.0832x; 1.0832x over previous
//
#include <hip/hip_runtime.h>
#include <hip/hip_bf16.h>

#define H 128
#define NHEADS 2
#define DK 96
#define DV 96
#define DFF 2048
#define VOUT 10000
#define VOUT_PAD 10112        // 79 * 128, zero-padded rows in Wt
#define NB 256
#define TT 43
#define NT (NB * TT)          // 11008
#define MD (NHEADS * DV)      // 192
#define MDP 256               // multi padded cols (K for woln1 GEMM)
#define QKVC 640              // packed qkv cols: 576 used + 64 pad

typedef short short8v __attribute__((ext_vector_type(8)));
typedef unsigned short ushort8v __attribute__((ext_vector_type(8)));
typedef float f32x4 __attribute__((ext_vector_type(4)));

__device__ __forceinline__ unsigned short f2bf(float f) {
    unsigned b = __float_as_uint(f);
    unsigned r = b + 0x7FFFu + ((b >> 16) & 1u);   // RTNE
    return (unsigned short)(r >> 16);
}
__device__ __forceinline__ float bf2f(unsigned short u) {
    return __uint_as_float((unsigned)u << 16);
}

// ---------------------------------------------------------------- embed (writes f32 x and bf16 xb)
__global__ __launch_bounds__(256) void embed_kernel(
    const int* __restrict__ inputs, const float* __restrict__ emb,
    const float* __restrict__ pos, float* __restrict__ x,
    unsigned short* __restrict__ xb) {
    int i = blockIdx.x * 256 + threadIdx.x;   // grid sized exactly NT*H/256
    int h = i & (H - 1);
    int nt = i >> 7;
    int t = nt % TT;
    float v = emb[inputs[nt] * H + h] + pos[t * H + h];
    x[i] = v;
    xb[i] = f2bf(v);
}

// ---------------------------------------------------------------- pack Wq/Wk/Wv -> Wqkv_t[640][128] bf16 + bias[640]
__global__ __launch_bounds__(256) void wqkv_pack_kernel(
    const float* __restrict__ Wq, const float* __restrict__ bq,
    const float* __restrict__ Wk, const float* __restrict__ bk,
    const float* __restrict__ Wv, const float* __restrict__ bv,
    unsigned short* __restrict__ Wt, float* __restrict__ bias) {
    int row = blockIdx.x * 256 + threadIdx.x;   // grid = 3 blocks
    if (row >= QKVC) return;
    unsigned short* dst = Wt + (size_t)row * H;
    if (row < 576) {
        int seg = row / 96;
        int d = row - seg * 96;
        int which = seg >> 1;                    // 0=q 1=k 2=v
        int head = seg & 1;
        const float* W  = (which == 0) ? Wq : (which == 1) ? Wk : Wv;
        const float* bi = (which == 0) ? bq : (which == 1) ? bk : bv;
        for (int h = 0; h < H; ++h) dst[h] = f2bf(W[((size_t)head * H + h) * DK + d]);
        bias[row] = bi[head * DK + d];
    } else {
        for (int h = 0; h < H; ++h) dst[h] = 0;
        bias[row] = 0.f;
    }
}

// ---------------------------------------------------------------- W1[128][2048] -> W1tb[2048][128] bf16
__global__ __launch_bounds__(256) void w1t_kernel(
    const float* __restrict__ W1, unsigned short* __restrict__ W1tb) {
    int n = blockIdx.x * 256 + threadIdx.x;   // grid = 8 blocks
    ushort8v* dst = (ushort8v*)(W1tb + (size_t)n * H);
    #pragma unroll
    for (int k16 = 0; k16 < 16; ++k16) {
        ushort8v v;
        #pragma unroll
        for (int j = 0; j < 8; ++j)
            v[j] = f2bf(W1[(size_t)(k16 * 8 + j) * DFF + n]);
        dst[k16] = v;
    }
}

// ---------------------------------------------------------------- W2[2048][128] -> W2tb[128][2048] bf16
__global__ __launch_bounds__(256) void w2t_kernel(
    const float* __restrict__ W2, unsigned short* __restrict__ W2tb) {
    int c = blockIdx.x;        // grid = 128 blocks
    int j = threadIdx.x;
    for (int k = j; k < DFF; k += 256)
        W2tb[(size_t)c * DFF + k] = f2bf(W2[(size_t)k * H + c]);
}

// ---------------------------------------------------------------- Wo[192][128] -> Wotb[128][256] bf16 (zero pad k>=192)
__global__ __launch_bounds__(256) void wotb_kernel(
    const float* __restrict__ Wo, unsigned short* __restrict__ Wot) {
    int idx = blockIdx.x * 256 + threadIdx.x;  // grid = 128 blocks -> 32768
    int c = idx >> 8, k = idx & 255;
    Wot[(size_t)c * MDP + k] = (k < MD) ? f2bf(Wo[(size_t)k * H + c]) : (unsigned short)0;
}

// ---------------------------------------------------------------- QKV GEMM (MFMA): qkvb = x @ Wqkv + bias, bf16 out
__global__ __launch_bounds__(256) void qkv_mfma_kernel(
    const unsigned short* __restrict__ xb, const unsigned short* __restrict__ Wt,
    const float* __restrict__ bias, unsigned short* __restrict__ qkvb) {
    __shared__ __align__(16) unsigned short As[128][128];  // 32 KB
    __shared__ __align__(16) unsigned short Bt[128][128];  // 32 KB
    int tid = threadIdx.x;
    int n0 = blockIdx.x * 128;                 // qkv-col tile (0..4)
    int m0 = blockIdx.y * 128;                 // token tile
    {
        const ushort8v* A8 = (const ushort8v*)(xb + (size_t)m0 * H);
        for (int qc = tid; qc < 2048; qc += 256) {
            int row = qc >> 4, o = qc & 15;
            int po = (o & 8) | ((o ^ row) & 7);
            *(ushort8v*)&As[row][po * 8] = A8[qc];
        }
    }
    {
        const ushort8v* B8 = (const ushort8v*)(Wt + (size_t)n0 * H);
        for (int qc = tid; qc < 2048; qc += 256) {
            int row = qc >> 4, o = qc & 15;
            int po = (o & 8) | ((o ^ row) & 7);
            *(ushort8v*)&Bt[row][po * 8] = B8[qc];
        }
    }
    __syncthreads();
    int lane = tid & 63;
    int w = tid >> 6;
    int wr = w >> 1, wc = w & 1;
    int rl = lane & 15, quad = lane >> 4;
    f32x4 acc[4][4];
    #pragma unroll
    for (int i = 0; i < 4; ++i)
        #pragma unroll
        for (int j = 0; j < 4; ++j) acc[i][j] = (f32x4){0.f, 0.f, 0.f, 0.f};
    #pragma unroll
    for (int kk = 0; kk < 4; ++kk) {
        int o = kk * 4 + quad;
        short8v a[4], b[4];
        #pragma unroll
        for (int mi = 0; mi < 4; ++mi) {
            int row = wr * 64 + mi * 16 + rl;
            int po = (o & 8) | ((o ^ row) & 7);
            a[mi] = *(const short8v*)&As[row][po * 8];
        }
        #pragma unroll
        for (int ni = 0; ni < 4; ++ni) {
            int cc = wc * 64 + ni * 16 + rl;
            int po = (o & 8) | ((o ^ cc) & 7);
            b[ni] = *(const short8v*)&Bt[cc][po * 8];
        }
        #pragma unroll
        for (int mi = 0; mi < 4; ++mi)
            #pragma unroll
            for (int ni = 0; ni < 4; ++ni)
                acc[mi][ni] = __builtin_amdgcn_mfma_f32_16x16x32_bf16(
                    a[mi], b[ni], acc[mi][ni], 0, 0, 0);
    }
    #pragma unroll
    for (int ni = 0; ni < 4; ++ni) {
        int col = n0 + wc * 64 + ni * 16 + rl;
        float bv = bias[col];
        #pragma unroll
        for (int mi = 0; mi < 4; ++mi) {
            int rbase = m0 + wr * 64 + mi * 16 + quad * 4;
            #pragma unroll
            for (int r = 0; r < 4; ++r)
                qkvb[(size_t)(rbase + r) * QKVC + col] = f2bf(acc[mi][ni][r] + bv);
        }
    }
}

// ---------------------------------------------------------------- attention core (vectorized bf16 staging; multi -> bf16 [NT][256])
__global__ __launch_bounds__(256) void attn_core_kernel(
    const unsigned short* __restrict__ qkvb, unsigned short* __restrict__ multi_b) {
    int blk = blockIdx.x;
    int n = blk / NHEADS, a = blk % NHEADS;
    int tid = threadIdx.x;
    __shared__ float qs[TT][DK];
    __shared__ float ks2[TT][DK];
    __shared__ float vs[TT][DV];
    __shared__ float ss[TT][TT + 1];
    // DK=96=12x8; 16B-aligned segments: elem off = a*96 + which*192 (bytes 192a+384w)
    for (int i = tid; i < TT * 12 * 3; i += 256) {
        int which = i / (TT * 12);
        int rem = i - which * (TT * 12);
        int t = rem / 12, c8 = rem - t * 12;
        ushort8v u = *(const ushort8v*)(qkvb + (size_t)(n * TT + t) * QKVC
                                        + a * DK + which * 192 + c8 * 8);
        float* dst = ((which == 0) ? &qs[t][0] : (which == 1) ? &ks2[t][0] : &vs[t][0]) + c8 * 8;
        #pragma unroll
        for (int j = 0; j < 8; ++j) dst[j] = bf2f(u[j]);
    }
    __syncthreads();
    const float scale = rsqrtf((float)DK);
    for (int o = tid; o < TT * TT; o += 256) {
        int t = o / TT, s = o - t * TT;
        float acc = 0.f;
        #pragma unroll 8
        for (int d = 0; d < DK; ++d) acc += qs[t][d] * ks2[s][d];
        ss[t][s] = acc * scale;
    }
    __syncthreads();
    if (tid < TT) {
        float m = -1e30f;
        for (int s = 0; s < TT; ++s) m = fmaxf(m, ss[tid][s]);
        float sum = 0.f;
        for (int s = 0; s < TT; ++s) { float e = __expf(ss[tid][s] - m); ss[tid][s] = e; sum += e; }
        float inv = 1.0f / sum;
        for (int s = 0; s < TT; ++s) ss[tid][s] *= inv;
    }
    __syncthreads();
    for (int o = tid; o < TT * DV; o += 256) {
        int t = o / DV, d = o - t * DV;
        float acc = 0.f;
        #pragma unroll 8
        for (int s = 0; s < TT; ++s) acc += ss[t][s] * vs[s][d];
        multi_b[(size_t)(n * TT + t) * MDP + a * DV + d] = f2bf(acc);
    }
    // pad cols [MD,MDP) stay 0xAA poison: finite bf16, multiplied by zeroed Wotb cols
}

// ---------------------------------------------------------------- Wo-GEMM + residual + LN1 (fused, MFMA)
// x1 = LN(x + multi_b @ Wo + bo); K=256 in 2 chunks of 128. Writes f32 x1 + bf16 x1b.
__global__ __launch_bounds__(256) void woln1_mfma_kernel(
    const unsigned short* __restrict__ mb, const unsigned short* __restrict__ Wot,
    const float* __restrict__ bo, const float* __restrict__ x,
    const float* __restrict__ g, const float* __restrict__ bln,
    float* __restrict__ x1, unsigned short* __restrict__ x1b) {
    __shared__ __align__(16) unsigned short As[128][128];  // 32 KB
    __shared__ __align__(16) unsigned short Bt[128][128];  // 32 KB
    int tid = threadIdx.x;
    int m0 = blockIdx.x * 128;
    int lane = tid & 63;
    int w = tid >> 6;
    int wr = w >> 1, wc = w & 1;
    int rl = lane & 15, quad = lane >> 4;
    f32x4 acc[4][4];
    #pragma unroll
    for (int i = 0; i < 4; ++i)
        #pragma unroll
        for (int j = 0; j < 4; ++j) acc[i][j] = (f32x4){0.f, 0.f, 0.f, 0.f};
    for (int kc = 0; kc < 2; ++kc) {
        for (int qc = tid; qc < 2048; qc += 256) {
            int row = qc >> 4, o = qc & 15;
            ushort8v v = *(const ushort8v*)(mb + (size_t)(m0 + row) * MDP + kc * 128 + o * 8);
            int po = (o & 8) | ((o ^ row) & 7);
            *(ushort8v*)&As[row][po * 8] = v;
        }
        for (int qc = tid; qc < 2048; qc += 256) {
            int row = qc >> 4, o = qc & 15;
            ushort8v v = *(const ushort8v*)(Wot + (size_t)row * MDP + kc * 128 + o * 8);
            int po = (o & 8) | ((o ^ row) & 7);
            *(ushort8v*)&Bt[row][po * 8] = v;
        }
        __syncthreads();
        #pragma unroll
        for (int kk = 0; kk < 4; ++kk) {
            int o = kk * 4 + quad;
            short8v a[4], b[4];
            #pragma unroll
            for (int mi = 0; mi < 4; ++mi) {
                int row = wr * 64 + mi * 16 + rl;
                int po = (o & 8) | ((o ^ row) & 7);
                a[mi] = *(const short8v*)&As[row][po * 8];
            }
            #pragma unroll
            for (int ni = 0; ni < 4; ++ni) {
                int cc = wc * 64 + ni * 16 + rl;
                int po = (o & 8) | ((o ^ cc) & 7);
                b[ni] = *(const short8v*)&Bt[cc][po * 8];
            }
            #pragma unroll
            for (int mi = 0; mi < 4; ++mi)
                #pragma unroll
                for (int ni = 0; ni < 4; ++ni)
                    acc[mi][ni] = __builtin_amdgcn_mfma_f32_16x16x32_bf16(
                        a[mi], b[ni], acc[mi][ni], 0, 0, 0);
        }
        __syncthreads();   // also protects As before scratch reuse below
    }
    // ---- fused epilogue: y = acc + bo + x ; LN over H=128 per row
    float gg[4], bb[4], bov[4];
    #pragma unroll
    for (int ni = 0; ni < 4; ++ni) {
        int col = wc * 64 + ni * 16 + rl;
        gg[ni] = g[col]; bb[ni] = bln[col]; bov[ni] = bo[col];
    }
    float sy[4][4], sy2[4][4];
    #pragma unroll
    for (int mi = 0; mi < 4; ++mi)
        #pragma unroll
        for (int r = 0; r < 4; ++r) { sy[mi][r] = 0.f; sy2[mi][r] = 0.f; }
    #pragma unroll
    for (int mi = 0; mi < 4; ++mi) {
        #pragma unroll
        for (int r = 0; r < 4; ++r) {
            int row = wr * 64 + mi * 16 + quad * 4 + r;
            #pragma unroll
            for (int ni = 0; ni < 4; ++ni) {
                int col = wc * 64 + ni * 16 + rl;
                float y = acc[mi][ni][r] + bov[ni] + x[(size_t)(m0 + row) * H + col];
                acc[mi][ni][r] = y;
                sy[mi][r] += y;
                sy2[mi][r] += y * y;
            }
        }
    }
    #pragma unroll
    for (int mi = 0; mi < 4; ++mi)
        #pragma unroll
        for (int r = 0; r < 4; ++r) {
            #pragma unroll
            for (int m = 1; m < 16; m <<= 1) {
                sy[mi][r]  += __shfl_xor(sy[mi][r],  m);
                sy2[mi][r] += __shfl_xor(sy2[mi][r], m);
            }
        }
    float* scr = (float*)&As[0][0];
    if (rl == 0) {
        #pragma unroll
        for (int mi = 0; mi < 4; ++mi)
            #pragma unroll
            for (int r = 0; r < 4; ++r) {
                int row = wr * 64 + mi * 16 + quad * 4 + r;
                scr[wc * 128 + row]       = sy[mi][r];
                scr[256 + wc * 128 + row] = sy2[mi][r];
            }
    }
    __syncthreads();
    #pragma unroll
    for (int mi = 0; mi < 4; ++mi) {
        #pragma unroll
        for (int r = 0; r < 4; ++r) {
            int row = wr * 64 + mi * 16 + quad * 4 + r;
            float tsy  = scr[row] + scr[128 + row];
            float tsy2 = scr[256 + row] + scr[384 + row];
            float mean = tsy * (1.0f / H);
            float var  = tsy2 * (1.0f / H) - mean * mean;
            float rstd = rsqrtf(var + 1e-5f);
            #pragma unroll
            for (int ni = 0; ni < 4; ++ni) {
                int col = wc * 64 + ni * 16 + rl;
                float v = (acc[mi][ni][r] - mean) * rstd * gg[ni] + bb[ni];
                size_t idx = (size_t)(m0 + row) * H + col;
                x1[idx] = v;
                x1b[idx] = f2bf(v);
            }
        }
    }
}

// ---------------------------------------------------------------- FF GEMM1: h = relu(x1 @ W1 + b1), bf16 out
__global__ __launch_bounds__(256) void ffh_kernel(
    const unsigned short* __restrict__ x1b, const unsigned short* __restrict__ W1tb,
    const float* __restrict__ b1, unsigned short* __restrict__ hb) {
    __shared__ __align__(16) unsigned short As[128][128];  // 32 KB
    __shared__ __align__(16) unsigned short Bt[128][128];  // 32 KB
    int tid = threadIdx.x;
    int n0 = blockIdx.x * 128;                 // ff-dim tile
    int m0 = blockIdx.y * 128;                 // token tile
    {
        const ushort8v* A8 = (const ushort8v*)(x1b + (size_t)m0 * H);
        for (int qc = tid; qc < 2048; qc += 256) {
            int row = qc >> 4, o = qc & 15;
            int po = (o & 8) | ((o ^ row) & 7);
            *(ushort8v*)&As[row][po * 8] = A8[qc];
        }
    }
    {
        const ushort8v* B8 = (const ushort8v*)(W1tb + (size_t)n0 * H);
        for (int qc = tid; qc < 2048; qc += 256) {
            int row = qc >> 4, o = qc & 15;
            int po = (o & 8) | ((o ^ row) & 7);
            *(ushort8v*)&Bt[row][po * 8] = B8[qc];
        }
    }
    __syncthreads();
    int lane = tid & 63;
    int w = tid >> 6;
    int wr = w >> 1, wc = w & 1;
    int rl = lane & 15, quad = lane >> 4;
    f32x4 acc[4][4];
    #pragma unroll
    for (int i = 0; i < 4; ++i)
        #pragma unroll
        for (int j = 0; j < 4; ++j) acc[i][j] = (f32x4){0.f, 0.f, 0.f, 0.f};
    #pragma unroll
    for (int kk = 0; kk < 4; ++kk) {
        int o = kk * 4 + quad;
        short8v a[4], b[4];
        #pragma unroll
        for (int mi = 0; mi < 4; ++mi) {
            int row = wr * 64 + mi * 16 + rl;
            int po = (o & 8) | ((o ^ row) & 7);
            a[mi] = *(const short8v*)&As[row][po * 8];
        }
        #pragma unroll
        for (int ni = 0; ni < 4; ++ni) {
            int cc = wc * 64 + ni * 16 + rl;
            int po = (o & 8) | ((o ^ cc) & 7);
            b[ni] = *(const short8v*)&Bt[cc][po * 8];
        }
        #pragma unroll
        for (int mi = 0; mi < 4; ++mi)
            #pragma unroll
            for (int ni = 0; ni < 4; ++ni)
                acc[mi][ni] = __builtin_amdgcn_mfma_f32_16x16x32_bf16(
                    a[mi], b[ni], acc[mi][ni], 0, 0, 0);
    }
    #pragma unroll
    for (int ni = 0; ni < 4; ++ni) {
        int col = n0 + wc * 64 + ni * 16 + rl;
        float bv = b1[col];
        #pragma unroll
        for (int mi = 0; mi < 4; ++mi) {
            int rbase = m0 + wr * 64 + mi * 16 + quad * 4;
            #pragma unroll
            for (int r = 0; r < 4; ++r)
                hb[(size_t)(rbase + r) * DFF + col] =
                    f2bf(fmaxf(acc[mi][ni][r] + bv, 0.f));
        }
    }
}

// ---------------------------------------------------------------- FF GEMM2 + residual + LN2 (fused): x2b = LN(h@W2 + b2 + x1)
__global__ __launch_bounds__(256) void ff2_ln2_kernel(
    const unsigned short* __restrict__ hb, const unsigned short* __restrict__ W2tb,
    const float* __restrict__ b2, const float* __restrict__ x1,
    const float* __restrict__ g, const float* __restrict__ bln,
    unsigned short* __restrict__ x2b) {
    __shared__ __align__(16) unsigned short As[128][128];  // 32 KB
    __shared__ __align__(16) unsigned short Bt[128][128];  // 32 KB
    int tid = threadIdx.x;
    int m0 = blockIdx.x * 128;
    int lane = tid & 63;
    int w = tid >> 6;
    int wr = w >> 1, wc = w & 1;
    int rl = lane & 15, quad = lane >> 4;
    f32x4 acc[4][4];
    #pragma unroll
    for (int i = 0; i < 4; ++i)
        #pragma unroll
        for (int j = 0; j < 4; ++j) acc[i][j] = (f32x4){0.f, 0.f, 0.f, 0.f};
    for (int kc = 0; kc < 16; ++kc) {
        for (int qc = tid; qc < 2048; qc += 256) {
            int row = qc >> 4, o = qc & 15;
            ushort8v v = *(const ushort8v*)(hb + (size_t)(m0 + row) * DFF + kc * 128 + o * 8);
            int po = (o & 8) | ((o ^ row) & 7);
            *(ushort8v*)&As[row][po * 8] = v;
        }
        for (int qc = tid; qc < 2048; qc += 256) {
            int row = qc >> 4, o = qc & 15;
            ushort8v v = *(const ushort8v*)(W2tb + (size_t)row * DFF + kc * 128 + o * 8);
            int po = (o & 8) | ((o ^ row) & 7);
            *(ushort8v*)&Bt[row][po * 8] = v;
        }
        __syncthreads();
        #pragma unroll
        for (int kk = 0; kk < 4; ++kk) {
            int o = kk * 4 + quad;
            short8v a[4], b[4];
            #pragma unroll
            for (int mi = 0; mi < 4; ++mi) {
                int row = wr * 64 + mi * 16 + rl;
                int po = (o & 8) | ((o ^ row) & 7);
                a[mi] = *(const short8v*)&As[row][po * 8];
            }
            #pragma unroll
            for (int ni = 0; ni < 4; ++ni) {
                int cc = wc * 64 + ni * 16 + rl;
                int po = (o & 8) | ((o ^ cc) & 7);
                b[ni] = *(const short8v*)&Bt[cc][po * 8];
            }
            #pragma unroll
            for (int mi = 0; mi < 4; ++mi)
                #pragma unroll
                for (int ni = 0; ni < 4; ++ni)
                    acc[mi][ni] = __builtin_amdgcn_mfma_f32_16x16x32_bf16(
                        a[mi], b[ni], acc[mi][ni], 0, 0, 0);
        }
        __syncthreads();   // after last iter, As is free for scratch reuse
    }
    // ---- fused epilogue: y = acc + b2 + x1 ; LN over H=128 per row; bf16 store
    float gg[4], bb[4], bov[4];
    #pragma unroll
    for (int ni = 0; ni < 4; ++ni) {
        int col = wc * 64 + ni * 16 + rl;
        gg[ni] = g[col]; bb[ni] = bln[col]; bov[ni] = b2[col];
    }
    float sy[4][4], sy2[4][4];
    #pragma unroll
    for (int mi = 0; mi < 4; ++mi)
        #pragma unroll
        for (int r = 0; r < 4; ++r) { sy[mi][r] = 0.f; sy2[mi][r] = 0.f; }
    #pragma unroll
    for (int mi = 0; mi < 4; ++mi) {
        #pragma unroll
        for (int r = 0; r < 4; ++r) {
            int row = wr * 64 + mi * 16 + quad * 4 + r;
            #pragma unroll
            for (int ni = 0; ni < 4; ++ni) {
                int col = wc * 64 + ni * 16 + rl;
                float y = acc[mi][ni][r] + bov[ni] + x1[(size_t)(m0 + row) * H + col];
                acc[mi][ni][r] = y;
                sy[mi][r] += y;
                sy2[mi][r] += y * y;
            }
        }
    }
    #pragma unroll
    for (int mi = 0; mi < 4; ++mi)
        #pragma unroll
        for (int r = 0; r < 4; ++r) {
            #pragma unroll
            for (int m = 1; m < 16; m <<= 1) {
                sy[mi][r]  += __shfl_xor(sy[mi][r],  m);
                sy2[mi][r] += __shfl_xor(sy2[mi][r], m);
            }
        }
    float* scr = (float*)&As[0][0];
    if (rl == 0) {
        #pragma unroll
        for (int mi = 0; mi < 4; ++mi)
            #pragma unroll
            for (int r = 0; r < 4; ++r) {
                int row = wr * 64 + mi * 16 + quad * 4 + r;
                scr[wc * 128 + row]       = sy[mi][r];
                scr[256 + wc * 128 + row] = sy2[mi][r];
            }
    }
    __syncthreads();
    #pragma unroll
    for (int mi = 0; mi < 4; ++mi) {
        #pragma unroll
        for (int r = 0; r < 4; ++r) {
            int row = wr * 64 + mi * 16 + quad * 4 + r;
            float tsy  = scr[row] + scr[128 + row];
            float tsy2 = scr[256 + row] + scr[384 + row];
            float mean = tsy * (1.0f / H);
            float var  = tsy2 * (1.0f / H) - mean * mean;
            float rstd = rsqrtf(var + 1e-5f);
            #pragma unroll
            for (int ni = 0; ni < 4; ++ni) {
                int col = wc * 64 + ni * 16 + rl;
                x2b[(size_t)(m0 + row) * H + col] =
                    f2bf((acc[mi][ni][r] - mean) * rstd * gg[ni] + bb[ni]);
            }
        }
    }
}

// ---------------------------------------------------------------- Wout fp32 [H][VOUT] -> bf16 transposed Wt[VOUT_PAD][H]
__global__ __launch_bounds__(256) void wtr_kernel(
    const float* __restrict__ W, unsigned short* __restrict__ Wt) {
    int n = blockIdx.x * 256 + threadIdx.x;   // grid = ceil(VOUT_PAD/256) = 40
    if (n >= VOUT_PAD) return;
    ushort8v* dst = (ushort8v*)(Wt + (size_t)n * H);
    if (n < VOUT) {
        #pragma unroll
        for (int k16 = 0; k16 < 16; ++k16) {
            ushort8v v;
            #pragma unroll
            for (int j = 0; j < 8; ++j)
                v[j] = f2bf(W[(size_t)(k16 * 8 + j) * VOUT + n]);
            dst[k16] = v;
        }
    } else {
        ushort8v z = {};
        #pragma unroll
        for (int k16 = 0; k16 < 16; ++k16) dst[k16] = z;
    }
}

// ---------------------------------------------------------------- vocab GEMM (bf16 MFMA), 2 m-tiles per block
// grid (79, 43): Bt staged once per block; two A-tiles computed against it.
__global__ __launch_bounds__(256) void out_gemm_mfma_kernel(
    const unsigned short* __restrict__ A, const unsigned short* __restrict__ Wt,
    const float* __restrict__ bias, float* __restrict__ C) {
    __shared__ __align__(16) unsigned short As[128][128];  // 32 KB
    __shared__ __align__(16) unsigned short Bt[128][128];  // 32 KB
    int tid = threadIdx.x;
    int n0 = blockIdx.x * 128;
    int lane = tid & 63;
    int w = tid >> 6;
    int wr = w >> 1, wc = w & 1;
    int rl = lane & 15, quad = lane >> 4;
    // stage B once
    {
        const ushort8v* B8 = (const ushort8v*)(Wt + (size_t)n0 * H);
        for (int qc = tid; qc < 2048; qc += 256) {
            int row = qc >> 4, o = qc & 15;
            int po = (o & 8) | ((o ^ row) & 7);
            *(ushort8v*)&Bt[row][po * 8] = B8[qc];
        }
    }
    float bv[4];
    #pragma unroll
    for (int ni = 0; ni < 4; ++ni) {
        int col = n0 + wc * 64 + ni * 16 + rl;
        bv[ni] = (col < VOUT) ? bias[col] : 0.f;
    }
    for (int half = 0; half < 2; ++half) {
        int m0 = (blockIdx.y * 2 + half) * 128;
        {
            const ushort8v* A8 = (const ushort8v*)(A + (size_t)m0 * H);
            for (int qc = tid; qc < 2048; qc += 256) {
                int row = qc >> 4, o = qc & 15;
                int po = (o & 8) | ((o ^ row) & 7);
                *(ushort8v*)&As[row][po * 8] = A8[qc];
            }
        }
        __syncthreads();
        f32x4 acc[4][4];
        #pragma unroll
        for (int i = 0; i < 4; ++i)
            #pragma unroll
            for (int j = 0; j < 4; ++j) acc[i][j] = (f32x4){0.f, 0.f, 0.f, 0.f};
        #pragma unroll
        for (int kk = 0; kk < 4; ++kk) {
            int o = kk * 4 + quad;
            short8v a[4], b[4];
            #pragma unroll
            for (int mi = 0; mi < 4; ++mi) {
                int row = wr * 64 + mi * 16 + rl;
                int po = (o & 8) | ((o ^ row) & 7);
                a[mi] = *(const short8v*)&As[row][po * 8];
            }
            #pragma unroll
            for (int ni = 0; ni < 4; ++ni) {
                int cc = wc * 64 + ni * 16 + rl;
                int po = (o & 8) | ((o ^ cc) & 7);
                b[ni] = *(const short8v*)&Bt[cc][po * 8];
            }
            #pragma unroll
            for (int mi = 0; mi < 4; ++mi)
                #pragma unroll
                for (int ni = 0; ni < 4; ++ni)
                    acc[mi][ni] = __builtin_amdgcn_mfma_f32_16x16x32_bf16(
                        a[mi], b[ni], acc[mi][ni], 0, 0, 0);
        }
        __syncthreads();   // all waves done reading As before next half restages
        #pragma unroll
        for (int ni = 0; ni < 4; ++ni) {
            int col = n0 + wc * 64 + ni * 16 + rl;
            if (col >= VOUT) continue;
            #pragma unroll
            for (int mi = 0; mi < 4; ++mi) {
                int rbase = m0 + wr * 64 + mi * 16 + quad * 4;
                #pragma unroll
                for (int r = 0; r < 4; ++r)
                    C[(size_t)(rbase + r) * VOUT + col] = acc[mi][ni][r] + bv[ni];
            }
        }
    }
}

// ---------------------------------------------------------------- launch
extern "C" void kernel_launch(void* const* d_in, const int* in_sizes, int n_in,
                              void* d_out, int out_size, void* d_ws, size_t ws_size,
                              hipStream_t stream) {
    const int*   inputs = (const int*)  d_in[0];
    const float* emb    = (const float*)d_in[1];
    const float* pos    = (const float*)d_in[2];
    const float* Wq     = (const float*)d_in[3];
    const float* bq     = (const float*)d_in[4];
    const float* Wk     = (const float*)d_in[5];
    const float* bk     = (const float*)d_in[6];
    const float* Wv     = (const float*)d_in[7];
    const float* bv     = (const float*)d_in[8];
    const float* Wo     = (const float*)d_in[9];
    const float* bo     = (const float*)d_in[10];
    const float* ln1g   = (const float*)d_in[11];
    const float* ln1b   = (const float*)d_in[12];
    const float* W1     = (const float*)d_in[13];
    const float* b1     = (const float*)d_in[14];
    const float* W2     = (const float*)d_in[15];
    const float* b2     = (const float*)d_in[16];
    const float* ln2g   = (const float*)d_in[17];
    const float* ln2b   = (const float*)d_in[18];
    const float* Wout   = (const float*)d_in[19];
    const float* bout   = (const float*)d_in[20];
    float* out = (float*)d_out;

    float* ws = (float*)d_ws;
    float* x      = ws;                                  // NT*H f32
    float* x1     = x + (size_t)NT * H;                  // NT*H f32
    float* bqkv   = x1 + (size_t)NT * H;                 // QKVC f32
    unsigned short* xb      = (unsigned short*)(bqkv + QKVC);            // NT*H bf16
    unsigned short* x1b     = xb + (size_t)NT * H;                       // NT*H bf16
    unsigned short* multi_b = x1b + (size_t)NT * H;                      // NT*MDP bf16
    unsigned short* x2b     = multi_b + (size_t)NT * MDP;                // NT*H bf16
    unsigned short* Woutb   = x2b + (size_t)NT * H;                      // VOUT_PAD*H bf16
    unsigned short* Wqkvb   = Woutb + (size_t)VOUT_PAD * H;              // QKVC*H bf16
    unsigned short* W1tb    = Wqkvb + (size_t)QKVC * H;                  // DFF*H bf16
    unsigned short* W2tb    = W1tb + (size_t)DFF * H;                    // H*DFF bf16
    unsigned short* Wotb    = W2tb + (size_t)H * DFF;                    // H*MDP bf16
    unsigned short* qkvb    = Wotb + (size_t)H * MDP;                    // NT*QKVC bf16
    unsigned short* hb      = qkvb + (size_t)NT * QKVC;                  // NT*DFF bf16

    wqkv_pack_kernel<<<(QKVC + 255) / 256, 256, 0, stream>>>(
        Wq, bq, Wk, bk, Wv, bv, Wqkvb, bqkv);
    wotb_kernel<<<H * MDP / 256, 256, 0, stream>>>(Wo, Wotb);
    w1t_kernel<<<DFF / 256, 256, 0, stream>>>(W1, W1tb);
    w2t_kernel<<<H, 256, 0, stream>>>(W2, W2tb);
    wtr_kernel<<<(VOUT_PAD + 255) / 256, 256, 0, stream>>>(Wout, Woutb);
    embed_kernel<<<NT * H / 256, 256, 0, stream>>>(inputs, emb, pos, x, xb);
    dim3 gqkv(QKVC / 128, NT / 128);
    qkv_mfma_kernel<<<gqkv, 256, 0, stream>>>(xb, Wqkvb, bqkv, qkvb);
    attn_core_kernel<<<NB * NHEADS, 256, 0, stream>>>(qkvb, multi_b);
    woln1_mfma_kernel<<<NT / 128, 256, 0, stream>>>(multi_b, Wotb, bo, x, ln1g, ln1b, x1, x1b);
    dim3 gff(DFF / 128, NT / 128);
    ffh_kernel<<<gff, 256, 0, stream>>>(x1b, W1tb, b1, hb);
    ff2_ln2_kernel<<<NT / 128, 256, 0, stream>>>(hb, W2tb, b2, x1, ln2g, ln2b, x2b);
    dim3 g5(VOUT_PAD / 128, NT / 256);
    out_gemm_mfma_kernel<<<g5, 256, 0, stream>>>(x2b, Woutb, bout, out);
}

// Round 10
// 707.732 us; speedup vs baseline: 1.1091x; 1.0239x over previous
//
#include <hip/hip_runtime.h>
#include <hip/hip_bf16.h>

#define H 128
#define NHEADS 2
#define DK 96
#define DV 96
#define DFF 2048
#define VOUT 10000
#define VOUT_PAD 10112        // 79 * 128, zero-padded rows in Wt
#define NB 256
#define TT 43
#define NT (NB * TT)          // 11008
#define MD (NHEADS * DV)      // 192
#define MDP 256               // multi padded cols (K for woln1 GEMM)
#define QKVC 640              // packed qkv cols: 576 used + 64 pad

typedef short short8v __attribute__((ext_vector_type(8)));
typedef unsigned short ushort8v __attribute__((ext_vector_type(8)));
typedef float f32x4 __attribute__((ext_vector_type(4)));

__device__ __forceinline__ unsigned short f2bf(float f) {
    unsigned b = __float_as_uint(f);
    unsigned r = b + 0x7FFFu + ((b >> 16) & 1u);   // RTNE
    return (unsigned short)(r >> 16);
}
__device__ __forceinline__ float bf2f(unsigned short u) {
    return __uint_as_float((unsigned)u << 16);
}

// ---------------------------------------------------------------- embed (writes f32 x and bf16 xb)
__global__ __launch_bounds__(256) void embed_kernel(
    const int* __restrict__ inputs, const float* __restrict__ emb,
    const float* __restrict__ pos, float* __restrict__ x,
    unsigned short* __restrict__ xb) {
    int i = blockIdx.x * 256 + threadIdx.x;   // grid sized exactly NT*H/256
    int h = i & (H - 1);
    int nt = i >> 7;
    int t = nt % TT;
    float v = emb[inputs[nt] * H + h] + pos[t * H + h];
    x[i] = v;
    xb[i] = f2bf(v);
}

// ---------------------------------------------------------------- pack Wq/Wk/Wv -> Wqkv_t[640][128] bf16 + bias[640]
__global__ __launch_bounds__(256) void wqkv_pack_kernel(
    const float* __restrict__ Wq, const float* __restrict__ bq,
    const float* __restrict__ Wk, const float* __restrict__ bk,
    const float* __restrict__ Wv, const float* __restrict__ bv,
    unsigned short* __restrict__ Wt, float* __restrict__ bias) {
    int row = blockIdx.x * 256 + threadIdx.x;   // grid = 3 blocks
    if (row >= QKVC) return;
    unsigned short* dst = Wt + (size_t)row * H;
    if (row < 576) {
        int seg = row / 96;
        int d = row - seg * 96;
        int which = seg >> 1;                    // 0=q 1=k 2=v
        int head = seg & 1;
        const float* W  = (which == 0) ? Wq : (which == 1) ? Wk : Wv;
        const float* bi = (which == 0) ? bq : (which == 1) ? bk : bv;
        for (int h = 0; h < H; ++h) dst[h] = f2bf(W[((size_t)head * H + h) * DK + d]);
        bias[row] = bi[head * DK + d];
    } else {
        for (int h = 0; h < H; ++h) dst[h] = 0;
        bias[row] = 0.f;
    }
}

// ---------------------------------------------------------------- W1[128][2048] -> W1tb[2048][128] bf16
__global__ __launch_bounds__(256) void w1t_kernel(
    const float* __restrict__ W1, unsigned short* __restrict__ W1tb) {
    int n = blockIdx.x * 256 + threadIdx.x;   // grid = 8 blocks
    ushort8v* dst = (ushort8v*)(W1tb + (size_t)n * H);
    #pragma unroll
    for (int k16 = 0; k16 < 16; ++k16) {
        ushort8v v;
        #pragma unroll
        for (int j = 0; j < 8; ++j)
            v[j] = f2bf(W1[(size_t)(k16 * 8 + j) * DFF + n]);
        dst[k16] = v;
    }
}

// ---------------------------------------------------------------- W2[2048][128] -> W2tb[128][2048] bf16
__global__ __launch_bounds__(256) void w2t_kernel(
    const float* __restrict__ W2, unsigned short* __restrict__ W2tb) {
    int c = blockIdx.x;        // grid = 128 blocks
    int j = threadIdx.x;
    for (int k = j; k < DFF; k += 256)
        W2tb[(size_t)c * DFF + k] = f2bf(W2[(size_t)k * H + c]);
}

// ---------------------------------------------------------------- Wo[192][128] -> Wotb[128][256] bf16 (zero pad k>=192)
__global__ __launch_bounds__(256) void wotb_kernel(
    const float* __restrict__ Wo, unsigned short* __restrict__ Wot) {
    int idx = blockIdx.x * 256 + threadIdx.x;  // grid = 128 blocks -> 32768
    int c = idx >> 8, k = idx & 255;
    Wot[(size_t)c * MDP + k] = (k < MD) ? f2bf(Wo[(size_t)k * H + c]) : (unsigned short)0;
}

// ---------------------------------------------------------------- QKV GEMM (MFMA): qkvb = x @ Wqkv + bias, bf16 out
__global__ __launch_bounds__(256) void qkv_mfma_kernel(
    const unsigned short* __restrict__ xb, const unsigned short* __restrict__ Wt,
    const float* __restrict__ bias, unsigned short* __restrict__ qkvb) {
    __shared__ __align__(16) unsigned short As[128][128];  // 32 KB
    __shared__ __align__(16) unsigned short Bt[128][128];  // 32 KB
    int tid = threadIdx.x;
    int n0 = blockIdx.x * 128;                 // qkv-col tile (0..4)
    int m0 = blockIdx.y * 128;                 // token tile
    {
        const ushort8v* A8 = (const ushort8v*)(xb + (size_t)m0 * H);
        for (int qc = tid; qc < 2048; qc += 256) {
            int row = qc >> 4, o = qc & 15;
            int po = (o & 8) | ((o ^ row) & 7);
            *(ushort8v*)&As[row][po * 8] = A8[qc];
        }
    }
    {
        const ushort8v* B8 = (const ushort8v*)(Wt + (size_t)n0 * H);
        for (int qc = tid; qc < 2048; qc += 256) {
            int row = qc >> 4, o = qc & 15;
            int po = (o & 8) | ((o ^ row) & 7);
            *(ushort8v*)&Bt[row][po * 8] = B8[qc];
        }
    }
    __syncthreads();
    int lane = tid & 63;
    int w = tid >> 6;
    int wr = w >> 1, wc = w & 1;
    int rl = lane & 15, quad = lane >> 4;
    f32x4 acc[4][4];
    #pragma unroll
    for (int i = 0; i < 4; ++i)
        #pragma unroll
        for (int j = 0; j < 4; ++j) acc[i][j] = (f32x4){0.f, 0.f, 0.f, 0.f};
    #pragma unroll
    for (int kk = 0; kk < 4; ++kk) {
        int o = kk * 4 + quad;
        short8v a[4], b[4];
        #pragma unroll
        for (int mi = 0; mi < 4; ++mi) {
            int row = wr * 64 + mi * 16 + rl;
            int po = (o & 8) | ((o ^ row) & 7);
            a[mi] = *(const short8v*)&As[row][po * 8];
        }
        #pragma unroll
        for (int ni = 0; ni < 4; ++ni) {
            int cc = wc * 64 + ni * 16 + rl;
            int po = (o & 8) | ((o ^ cc) & 7);
            b[ni] = *(const short8v*)&Bt[cc][po * 8];
        }
        #pragma unroll
        for (int mi = 0; mi < 4; ++mi)
            #pragma unroll
            for (int ni = 0; ni < 4; ++ni)
                acc[mi][ni] = __builtin_amdgcn_mfma_f32_16x16x32_bf16(
                    a[mi], b[ni], acc[mi][ni], 0, 0, 0);
    }
    #pragma unroll
    for (int ni = 0; ni < 4; ++ni) {
        int col = n0 + wc * 64 + ni * 16 + rl;
        float bv = bias[col];
        #pragma unroll
        for (int mi = 0; mi < 4; ++mi) {
            int rbase = m0 + wr * 64 + mi * 16 + quad * 4;
            #pragma unroll
            for (int r = 0; r < 4; ++r)
                qkvb[(size_t)(rbase + r) * QKVC + col] = f2bf(acc[mi][ni][r] + bv);
        }
    }
}

// ---------------------------------------------------------------- attention core (vectorized bf16 staging; multi -> bf16 [NT][256])
__global__ __launch_bounds__(256) void attn_core_kernel(
    const unsigned short* __restrict__ qkvb, unsigned short* __restrict__ multi_b) {
    int blk = blockIdx.x;
    int n = blk / NHEADS, a = blk % NHEADS;
    int tid = threadIdx.x;
    __shared__ float qs[TT][DK];
    __shared__ float ks2[TT][DK];
    __shared__ float vs[TT][DV];
    __shared__ float ss[TT][TT + 1];
    // DK=96=12x8; 16B-aligned segments: elem off = a*96 + which*192
    for (int i = tid; i < TT * 12 * 3; i += 256) {
        int which = i / (TT * 12);
        int rem = i - which * (TT * 12);
        int t = rem / 12, c8 = rem - t * 12;
        ushort8v u = *(const ushort8v*)(qkvb + (size_t)(n * TT + t) * QKVC
                                        + a * DK + which * 192 + c8 * 8);
        float* dst = ((which == 0) ? &qs[t][0] : (which == 1) ? &ks2[t][0] : &vs[t][0]) + c8 * 8;
        #pragma unroll
        for (int j = 0; j < 8; ++j) dst[j] = bf2f(u[j]);
    }
    __syncthreads();
    const float scale = rsqrtf((float)DK);
    for (int o = tid; o < TT * TT; o += 256) {
        int t = o / TT, s = o - t * TT;
        float acc = 0.f;
        #pragma unroll 8
        for (int d = 0; d < DK; ++d) acc += qs[t][d] * ks2[s][d];
        ss[t][s] = acc * scale;
    }
    __syncthreads();
    if (tid < TT) {
        float m = -1e30f;
        for (int s = 0; s < TT; ++s) m = fmaxf(m, ss[tid][s]);
        float sum = 0.f;
        for (int s = 0; s < TT; ++s) { float e = __expf(ss[tid][s] - m); ss[tid][s] = e; sum += e; }
        float inv = 1.0f / sum;
        for (int s = 0; s < TT; ++s) ss[tid][s] *= inv;
    }
    __syncthreads();
    for (int o = tid; o < TT * DV; o += 256) {
        int t = o / DV, d = o - t * DV;
        float acc = 0.f;
        #pragma unroll 8
        for (int s = 0; s < TT; ++s) acc += ss[t][s] * vs[s][d];
        multi_b[(size_t)(n * TT + t) * MDP + a * DV + d] = f2bf(acc);
    }
    // pad cols [MD,MDP) stay 0xAA poison: finite bf16, multiplied by zeroed Wotb cols
}

// ---------------------------------------------------------------- Wo-GEMM + residual + LN1 (fused, MFMA)
__global__ __launch_bounds__(256) void woln1_mfma_kernel(
    const unsigned short* __restrict__ mb, const unsigned short* __restrict__ Wot,
    const float* __restrict__ bo, const float* __restrict__ x,
    const float* __restrict__ g, const float* __restrict__ bln,
    float* __restrict__ x1, unsigned short* __restrict__ x1b) {
    __shared__ __align__(16) unsigned short As[128][128];  // 32 KB
    __shared__ __align__(16) unsigned short Bt[128][128];  // 32 KB
    int tid = threadIdx.x;
    int m0 = blockIdx.x * 128;
    int lane = tid & 63;
    int w = tid >> 6;
    int wr = w >> 1, wc = w & 1;
    int rl = lane & 15, quad = lane >> 4;
    f32x4 acc[4][4];
    #pragma unroll
    for (int i = 0; i < 4; ++i)
        #pragma unroll
        for (int j = 0; j < 4; ++j) acc[i][j] = (f32x4){0.f, 0.f, 0.f, 0.f};
    for (int kc = 0; kc < 2; ++kc) {
        for (int qc = tid; qc < 2048; qc += 256) {
            int row = qc >> 4, o = qc & 15;
            ushort8v v = *(const ushort8v*)(mb + (size_t)(m0 + row) * MDP + kc * 128 + o * 8);
            int po = (o & 8) | ((o ^ row) & 7);
            *(ushort8v*)&As[row][po * 8] = v;
        }
        for (int qc = tid; qc < 2048; qc += 256) {
            int row = qc >> 4, o = qc & 15;
            ushort8v v = *(const ushort8v*)(Wot + (size_t)row * MDP + kc * 128 + o * 8);
            int po = (o & 8) | ((o ^ row) & 7);
            *(ushort8v*)&Bt[row][po * 8] = v;
        }
        __syncthreads();
        #pragma unroll
        for (int kk = 0; kk < 4; ++kk) {
            int o = kk * 4 + quad;
            short8v a[4], b[4];
            #pragma unroll
            for (int mi = 0; mi < 4; ++mi) {
                int row = wr * 64 + mi * 16 + rl;
                int po = (o & 8) | ((o ^ row) & 7);
                a[mi] = *(const short8v*)&As[row][po * 8];
            }
            #pragma unroll
            for (int ni = 0; ni < 4; ++ni) {
                int cc = wc * 64 + ni * 16 + rl;
                int po = (o & 8) | ((o ^ cc) & 7);
                b[ni] = *(const short8v*)&Bt[cc][po * 8];
            }
            #pragma unroll
            for (int mi = 0; mi < 4; ++mi)
                #pragma unroll
                for (int ni = 0; ni < 4; ++ni)
                    acc[mi][ni] = __builtin_amdgcn_mfma_f32_16x16x32_bf16(
                        a[mi], b[ni], acc[mi][ni], 0, 0, 0);
        }
        __syncthreads();   // also protects As before scratch reuse below
    }
    // ---- fused epilogue: y = acc + bo + x ; LN over H=128 per row
    float gg[4], bb[4], bov[4];
    #pragma unroll
    for (int ni = 0; ni < 4; ++ni) {
        int col = wc * 64 + ni * 16 + rl;
        gg[ni] = g[col]; bb[ni] = bln[col]; bov[ni] = bo[col];
    }
    float sy[4][4], sy2[4][4];
    #pragma unroll
    for (int mi = 0; mi < 4; ++mi)
        #pragma unroll
        for (int r = 0; r < 4; ++r) { sy[mi][r] = 0.f; sy2[mi][r] = 0.f; }
    #pragma unroll
    for (int mi = 0; mi < 4; ++mi) {
        #pragma unroll
        for (int r = 0; r < 4; ++r) {
            int row = wr * 64 + mi * 16 + quad * 4 + r;
            #pragma unroll
            for (int ni = 0; ni < 4; ++ni) {
                int col = wc * 64 + ni * 16 + rl;
                float y = acc[mi][ni][r] + bov[ni] + x[(size_t)(m0 + row) * H + col];
                acc[mi][ni][r] = y;
                sy[mi][r] += y;
                sy2[mi][r] += y * y;
            }
        }
    }
    #pragma unroll
    for (int mi = 0; mi < 4; ++mi)
        #pragma unroll
        for (int r = 0; r < 4; ++r) {
            #pragma unroll
            for (int m = 1; m < 16; m <<= 1) {
                sy[mi][r]  += __shfl_xor(sy[mi][r],  m);
                sy2[mi][r] += __shfl_xor(sy2[mi][r], m);
            }
        }
    float* scr = (float*)&As[0][0];
    if (rl == 0) {
        #pragma unroll
        for (int mi = 0; mi < 4; ++mi)
            #pragma unroll
            for (int r = 0; r < 4; ++r) {
                int row = wr * 64 + mi * 16 + quad * 4 + r;
                scr[wc * 128 + row]       = sy[mi][r];
                scr[256 + wc * 128 + row] = sy2[mi][r];
            }
    }
    __syncthreads();
    #pragma unroll
    for (int mi = 0; mi < 4; ++mi) {
        #pragma unroll
        for (int r = 0; r < 4; ++r) {
            int row = wr * 64 + mi * 16 + quad * 4 + r;
            float tsy  = scr[row] + scr[128 + row];
            float tsy2 = scr[256 + row] + scr[384 + row];
            float mean = tsy * (1.0f / H);
            float var  = tsy2 * (1.0f / H) - mean * mean;
            float rstd = rsqrtf(var + 1e-5f);
            #pragma unroll
            for (int ni = 0; ni < 4; ++ni) {
                int col = wc * 64 + ni * 16 + rl;
                float v = (acc[mi][ni][r] - mean) * rstd * gg[ni] + bb[ni];
                size_t idx = (size_t)(m0 + row) * H + col;
                x1[idx] = v;
                x1b[idx] = f2bf(v);
            }
        }
    }
}

// ---------------------------------------------------------------- FF GEMM1: h = relu(x1 @ W1 + b1), bf16 out
__global__ __launch_bounds__(256) void ffh_kernel(
    const unsigned short* __restrict__ x1b, const unsigned short* __restrict__ W1tb,
    const float* __restrict__ b1, unsigned short* __restrict__ hb) {
    __shared__ __align__(16) unsigned short As[128][128];  // 32 KB
    __shared__ __align__(16) unsigned short Bt[128][128];  // 32 KB
    int tid = threadIdx.x;
    int n0 = blockIdx.x * 128;                 // ff-dim tile
    int m0 = blockIdx.y * 128;                 // token tile
    {
        const ushort8v* A8 = (const ushort8v*)(x1b + (size_t)m0 * H);
        for (int qc = tid; qc < 2048; qc += 256) {
            int row = qc >> 4, o = qc & 15;
            int po = (o & 8) | ((o ^ row) & 7);
            *(ushort8v*)&As[row][po * 8] = A8[qc];
        }
    }
    {
        const ushort8v* B8 = (const ushort8v*)(W1tb + (size_t)n0 * H);
        for (int qc = tid; qc < 2048; qc += 256) {
            int row = qc >> 4, o = qc & 15;
            int po = (o & 8) | ((o ^ row) & 7);
            *(ushort8v*)&Bt[row][po * 8] = B8[qc];
        }
    }
    __syncthreads();
    int lane = tid & 63;
    int w = tid >> 6;
    int wr = w >> 1, wc = w & 1;
    int rl = lane & 15, quad = lane >> 4;
    f32x4 acc[4][4];
    #pragma unroll
    for (int i = 0; i < 4; ++i)
        #pragma unroll
        for (int j = 0; j < 4; ++j) acc[i][j] = (f32x4){0.f, 0.f, 0.f, 0.f};
    #pragma unroll
    for (int kk = 0; kk < 4; ++kk) {
        int o = kk * 4 + quad;
        short8v a[4], b[4];
        #pragma unroll
        for (int mi = 0; mi < 4; ++mi) {
            int row = wr * 64 + mi * 16 + rl;
            int po = (o & 8) | ((o ^ row) & 7);
            a[mi] = *(const short8v*)&As[row][po * 8];
        }
        #pragma unroll
        for (int ni = 0; ni < 4; ++ni) {
            int cc = wc * 64 + ni * 16 + rl;
            int po = (o & 8) | ((o ^ cc) & 7);
            b[ni] = *(const short8v*)&Bt[cc][po * 8];
        }
        #pragma unroll
        for (int mi = 0; mi < 4; ++mi)
            #pragma unroll
            for (int ni = 0; ni < 4; ++ni)
                acc[mi][ni] = __builtin_amdgcn_mfma_f32_16x16x32_bf16(
                    a[mi], b[ni], acc[mi][ni], 0, 0, 0);
    }
    #pragma unroll
    for (int ni = 0; ni < 4; ++ni) {
        int col = n0 + wc * 64 + ni * 16 + rl;
        float bv = b1[col];
        #pragma unroll
        for (int mi = 0; mi < 4; ++mi) {
            int rbase = m0 + wr * 64 + mi * 16 + quad * 4;
            #pragma unroll
            for (int r = 0; r < 4; ++r)
                hb[(size_t)(rbase + r) * DFF + col] =
                    f2bf(fmaxf(acc[mi][ni][r] + bv, 0.f));
        }
    }
}

// ---------------------------------------------------------------- FF GEMM2 split-K: partial[ks] = h @ W2 over K range [ks*512,(ks+1)*512)
__global__ __launch_bounds__(256) void ff2_splitk_kernel(
    const unsigned short* __restrict__ hb, const unsigned short* __restrict__ W2tb,
    float* __restrict__ pws) {
    __shared__ __align__(16) unsigned short As[128][128];  // 32 KB
    __shared__ __align__(16) unsigned short Bt[128][128];  // 32 KB
    int tid = threadIdx.x;
    int m0 = blockIdx.x * 128;
    int ks = blockIdx.y;                      // 0..3
    int lane = tid & 63;
    int w = tid >> 6;
    int wr = w >> 1, wc = w & 1;
    int rl = lane & 15, quad = lane >> 4;
    f32x4 acc[4][4];
    #pragma unroll
    for (int i = 0; i < 4; ++i)
        #pragma unroll
        for (int j = 0; j < 4; ++j) acc[i][j] = (f32x4){0.f, 0.f, 0.f, 0.f};
    for (int kci = 0; kci < 4; ++kci) {
        int kc = ks * 4 + kci;
        for (int qc = tid; qc < 2048; qc += 256) {
            int row = qc >> 4, o = qc & 15;
            ushort8v v = *(const ushort8v*)(hb + (size_t)(m0 + row) * DFF + kc * 128 + o * 8);
            int po = (o & 8) | ((o ^ row) & 7);
            *(ushort8v*)&As[row][po * 8] = v;
        }
        for (int qc = tid; qc < 2048; qc += 256) {
            int row = qc >> 4, o = qc & 15;
            ushort8v v = *(const ushort8v*)(W2tb + (size_t)row * DFF + kc * 128 + o * 8);
            int po = (o & 8) | ((o ^ row) & 7);
            *(ushort8v*)&Bt[row][po * 8] = v;
        }
        __syncthreads();
        #pragma unroll
        for (int kk = 0; kk < 4; ++kk) {
            int o = kk * 4 + quad;
            short8v a[4], b[4];
            #pragma unroll
            for (int mi = 0; mi < 4; ++mi) {
                int row = wr * 64 + mi * 16 + rl;
                int po = (o & 8) | ((o ^ row) & 7);
                a[mi] = *(const short8v*)&As[row][po * 8];
            }
            #pragma unroll
            for (int ni = 0; ni < 4; ++ni) {
                int cc = wc * 64 + ni * 16 + rl;
                int po = (o & 8) | ((o ^ cc) & 7);
                b[ni] = *(const short8v*)&Bt[cc][po * 8];
            }
            #pragma unroll
            for (int mi = 0; mi < 4; ++mi)
                #pragma unroll
                for (int ni = 0; ni < 4; ++ni)
                    acc[mi][ni] = __builtin_amdgcn_mfma_f32_16x16x32_bf16(
                        a[mi], b[ni], acc[mi][ni], 0, 0, 0);
        }
        __syncthreads();
    }
    // store f32 partial (no bias/residual/LN here)
    #pragma unroll
    for (int ni = 0; ni < 4; ++ni) {
        int col = wc * 64 + ni * 16 + rl;
        #pragma unroll
        for (int mi = 0; mi < 4; ++mi) {
            int rbase = m0 + wr * 64 + mi * 16 + quad * 4;
            #pragma unroll
            for (int r = 0; r < 4; ++r)
                pws[((size_t)ks * NT + rbase + r) * H + col] = acc[mi][ni][r];
        }
    }
}

// ---------------------------------------------------------------- reduce 4 partials + b2 + residual + LN2 -> x2b bf16
// 86 blocks x 256 threads; thread owns half a row (64 cols) in registers
__global__ __launch_bounds__(256) void ff2red_ln2_kernel(
    const float* __restrict__ pws, const float* __restrict__ b2,
    const float* __restrict__ x1, const float* __restrict__ g,
    const float* __restrict__ bln, unsigned short* __restrict__ x2b) {
    const size_t NTH = (size_t)NT * H;
    int m0 = blockIdx.x * 128;
    int tid = threadIdx.x;
    int row = tid >> 1, half = tid & 1;
    size_t rbase = (size_t)(m0 + row) * H + half * 64;
    int cbase = half * 64;
    f32x4 y4[16];
    float sy = 0.f, sy2 = 0.f;
    #pragma unroll
    for (int i = 0; i < 16; ++i) {
        f32x4 p0 = *(const f32x4*)(pws + 0 * NTH + rbase + i * 4);
        f32x4 p1 = *(const f32x4*)(pws + 1 * NTH + rbase + i * 4);
        f32x4 p2 = *(const f32x4*)(pws + 2 * NTH + rbase + i * 4);
        f32x4 p3 = *(const f32x4*)(pws + 3 * NTH + rbase + i * 4);
        f32x4 xr = *(const f32x4*)(x1 + rbase + i * 4);
        f32x4 bb = *(const f32x4*)(b2 + cbase + i * 4);
        f32x4 y = p0 + p1 + p2 + p3 + xr + bb;
        y4[i] = y;
        #pragma unroll
        for (int j = 0; j < 4; ++j) { sy += y[j]; sy2 += y[j] * y[j]; }
    }
    // row's two threads are adjacent lanes
    sy  += __shfl_xor(sy, 1);
    sy2 += __shfl_xor(sy2, 1);
    float mean = sy * (1.0f / H);
    float var  = sy2 * (1.0f / H) - mean * mean;
    float rstd = rsqrtf(var + 1e-5f);
    #pragma unroll
    for (int i = 0; i < 16; i += 2) {
        f32x4 g0 = *(const f32x4*)(g + cbase + i * 4);
        f32x4 b0 = *(const f32x4*)(bln + cbase + i * 4);
        f32x4 g1 = *(const f32x4*)(g + cbase + i * 4 + 4);
        f32x4 b1v = *(const f32x4*)(bln + cbase + i * 4 + 4);
        ushort8v o;
        #pragma unroll
        for (int j = 0; j < 4; ++j) {
            o[j]     = f2bf((y4[i][j]     - mean) * rstd * g0[j] + b0[j]);
            o[j + 4] = f2bf((y4[i + 1][j] - mean) * rstd * g1[j] + b1v[j]);
        }
        *(ushort8v*)(x2b + rbase + i * 4) = o;
    }
}

// ---------------------------------------------------------------- Wout fp32 [H][VOUT] -> bf16 transposed Wt[VOUT_PAD][H]
__global__ __launch_bounds__(256) void wtr_kernel(
    const float* __restrict__ W, unsigned short* __restrict__ Wt) {
    int n = blockIdx.x * 256 + threadIdx.x;   // grid = ceil(VOUT_PAD/256) = 40
    if (n >= VOUT_PAD) return;
    ushort8v* dst = (ushort8v*)(Wt + (size_t)n * H);
    if (n < VOUT) {
        #pragma unroll
        for (int k16 = 0; k16 < 16; ++k16) {
            ushort8v v;
            #pragma unroll
            for (int j = 0; j < 8; ++j)
                v[j] = f2bf(W[(size_t)(k16 * 8 + j) * VOUT + n]);
            dst[k16] = v;
        }
    } else {
        ushort8v z = {};
        #pragma unroll
        for (int k16 = 0; k16 < 16; ++k16) dst[k16] = z;
    }
}

// ---------------------------------------------------------------- vocab GEMM (bf16 MFMA), 2 m-tiles per block
__global__ __launch_bounds__(256) void out_gemm_mfma_kernel(
    const unsigned short* __restrict__ A, const unsigned short* __restrict__ Wt,
    const float* __restrict__ bias, float* __restrict__ C) {
    __shared__ __align__(16) unsigned short As[128][128];  // 32 KB
    __shared__ __align__(16) unsigned short Bt[128][128];  // 32 KB
    int tid = threadIdx.x;
    int n0 = blockIdx.x * 128;
    int lane = tid & 63;
    int w = tid >> 6;
    int wr = w >> 1, wc = w & 1;
    int rl = lane & 15, quad = lane >> 4;
    // stage B once
    {
        const ushort8v* B8 = (const ushort8v*)(Wt + (size_t)n0 * H);
        for (int qc = tid; qc < 2048; qc += 256) {
            int row = qc >> 4, o = qc & 15;
            int po = (o & 8) | ((o ^ row) & 7);
            *(ushort8v*)&Bt[row][po * 8] = B8[qc];
        }
    }
    float bv[4];
    #pragma unroll
    for (int ni = 0; ni < 4; ++ni) {
        int col = n0 + wc * 64 + ni * 16 + rl;
        bv[ni] = (col < VOUT) ? bias[col] : 0.f;
    }
    for (int half = 0; half < 2; ++half) {
        int m0 = (blockIdx.y * 2 + half) * 128;
        {
            const ushort8v* A8 = (const ushort8v*)(A + (size_t)m0 * H);
            for (int qc = tid; qc < 2048; qc += 256) {
                int row = qc >> 4, o = qc & 15;
                int po = (o & 8) | ((o ^ row) & 7);
                *(ushort8v*)&As[row][po * 8] = A8[qc];
            }
        }
        __syncthreads();
        f32x4 acc[4][4];
        #pragma unroll
        for (int i = 0; i < 4; ++i)
            #pragma unroll
            for (int j = 0; j < 4; ++j) acc[i][j] = (f32x4){0.f, 0.f, 0.f, 0.f};
        #pragma unroll
        for (int kk = 0; kk < 4; ++kk) {
            int o = kk * 4 + quad;
            short8v a[4], b[4];
            #pragma unroll
            for (int mi = 0; mi < 4; ++mi) {
                int row = wr * 64 + mi * 16 + rl;
                int po = (o & 8) | ((o ^ row) & 7);
                a[mi] = *(const short8v*)&As[row][po * 8];
            }
            #pragma unroll
            for (int ni = 0; ni < 4; ++ni) {
                int cc = wc * 64 + ni * 16 + rl;
                int po = (o & 8) | ((o ^ cc) & 7);
                b[ni] = *(const short8v*)&Bt[cc][po * 8];
            }
            #pragma unroll
            for (int mi = 0; mi < 4; ++mi)
                #pragma unroll
                for (int ni = 0; ni < 4; ++ni)
                    acc[mi][ni] = __builtin_amdgcn_mfma_f32_16x16x32_bf16(
                        a[mi], b[ni], acc[mi][ni], 0, 0, 0);
        }
        __syncthreads();   // all waves done reading As before next half restages
        #pragma unroll
        for (int ni = 0; ni < 4; ++ni) {
            int col = n0 + wc * 64 + ni * 16 + rl;
            if (col >= VOUT) continue;
            #pragma unroll
            for (int mi = 0; mi < 4; ++mi) {
                int rbase = m0 + wr * 64 + mi * 16 + quad * 4;
                #pragma unroll
                for (int r = 0; r < 4; ++r)
                    C[(size_t)(rbase + r) * VOUT + col] = acc[mi][ni][r] + bv[ni];
            }
        }
    }
}

// ---------------------------------------------------------------- launch
extern "C" void kernel_launch(void* const* d_in, const int* in_sizes, int n_in,
                              void* d_out, int out_size, void* d_ws, size_t ws_size,
                              hipStream_t stream) {
    const int*   inputs = (const int*)  d_in[0];
    const float* emb    = (const float*)d_in[1];
    const float* pos    = (const float*)d_in[2];
    const float* Wq     = (const float*)d_in[3];
    const float* bq     = (const float*)d_in[4];
    const float* Wk     = (const float*)d_in[5];
    const float* bk     = (const float*)d_in[6];
    const float* Wv     = (const float*)d_in[7];
    const float* bv     = (const float*)d_in[8];
    const float* Wo     = (const float*)d_in[9];
    const float* bo     = (const float*)d_in[10];
    const float* ln1g   = (const float*)d_in[11];
    const float* ln1b   = (const float*)d_in[12];
    const float* W1     = (const float*)d_in[13];
    const float* b1     = (const float*)d_in[14];
    const float* W2     = (const float*)d_in[15];
    const float* b2     = (const float*)d_in[16];
    const float* ln2g   = (const float*)d_in[17];
    const float* ln2b   = (const float*)d_in[18];
    const float* Wout   = (const float*)d_in[19];
    const float* bout   = (const float*)d_in[20];
    float* out = (float*)d_out;

    float* ws = (float*)d_ws;
    float* x      = ws;                                  // NT*H f32
    float* x1     = x + (size_t)NT * H;                  // NT*H f32
    float* pws    = x1 + (size_t)NT * H;                 // 4*NT*H f32 (split-K partials)
    float* bqkv   = pws + (size_t)4 * NT * H;            // QKVC f32
    unsigned short* xb      = (unsigned short*)(bqkv + QKVC);            // NT*H bf16
    unsigned short* x1b     = xb + (size_t)NT * H;                       // NT*H bf16
    unsigned short* multi_b = x1b + (size_t)NT * H;                      // NT*MDP bf16
    unsigned short* x2b     = multi_b + (size_t)NT * MDP;                // NT*H bf16
    unsigned short* Woutb   = x2b + (size_t)NT * H;                      // VOUT_PAD*H bf16
    unsigned short* Wqkvb   = Woutb + (size_t)VOUT_PAD * H;              // QKVC*H bf16
    unsigned short* W1tb    = Wqkvb + (size_t)QKVC * H;                  // DFF*H bf16
    unsigned short* W2tb    = W1tb + (size_t)DFF * H;                    // H*DFF bf16
    unsigned short* Wotb    = W2tb + (size_t)H * DFF;                    // H*MDP bf16
    unsigned short* qkvb    = Wotb + (size_t)H * MDP;                    // NT*QKVC bf16
    unsigned short* hb      = qkvb + (size_t)NT * QKVC;                  // NT*DFF bf16

    wqkv_pack_kernel<<<(QKVC + 255) / 256, 256, 0, stream>>>(
        Wq, bq, Wk, bk, Wv, bv, Wqkvb, bqkv);
    wotb_kernel<<<H * MDP / 256, 256, 0, stream>>>(Wo, Wotb);
    w1t_kernel<<<DFF / 256, 256, 0, stream>>>(W1, W1tb);
    w2t_kernel<<<H, 256, 0, stream>>>(W2, W2tb);
    wtr_kernel<<<(VOUT_PAD + 255) / 256, 256, 0, stream>>>(Wout, Woutb);
    embed_kernel<<<NT * H / 256, 256, 0, stream>>>(inputs, emb, pos, x, xb);
    dim3 gqkv(QKVC / 128, NT / 128);
    qkv_mfma_kernel<<<gqkv, 256, 0, stream>>>(xb, Wqkvb, bqkv, qkvb);
    attn_core_kernel<<<NB * NHEADS, 256, 0, stream>>>(qkvb, multi_b);
    woln1_mfma_kernel<<<NT / 128, 256, 0, stream>>>(multi_b, Wotb, bo, x, ln1g, ln1b, x1, x1b);
    dim3 gff(DFF / 128, NT / 128);
    ffh_kernel<<<gff, 256, 0, stream>>>(x1b, W1tb, b1, hb);
    dim3 gsk(NT / 128, 4);
    ff2_splitk_kernel<<<gsk, 256, 0, stream>>>(hb, W2tb, pws);
    ff2red_ln2_kernel<<<NT / 128, 256, 0, stream>>>(pws, b2, x1, ln2g, ln2b, x2b);
    dim3 g5(VOUT_PAD / 128, NT / 256);
    out_gemm_mfma_kernel<<<g5, 256, 0, stream>>>(x2b, Woutb, bout, out);
}